// Round 5
// baseline (2400.563 us; speedup 1.0000x reference)
//
#include <hip/hip_runtime.h>
#include <hip/hip_bf16.h>
#include <cmath>

typedef __bf16 bf16;
typedef __attribute__((ext_vector_type(8))) __bf16 bf16x8;
typedef __attribute__((ext_vector_type(4))) float f32x4;

#define DEV __device__ __forceinline__

constexpr int HDIM = 768, NHEADS = 12, DHEAD = 64, IDIM = 3072, BATCH = 8, SEQ = 512;
constexpr int MTOK = BATCH * SEQ;   // 4096 tokens
constexpr int H3 = 3 * HDIM;        // 2304
constexpr float SCALE = 0.125f;     // 1/sqrt(64)

DEV void gld16(const bf16* g, bf16* l) {
  __builtin_amdgcn_global_load_lds((const __attribute__((address_space(1))) void*)g,
                                   (__attribute__((address_space(3))) void*)l, 16, 0, 0);
}
DEV void gld16f(const float* g, float* l) {
  __builtin_amdgcn_global_load_lds((const __attribute__((address_space(1))) void*)g,
                                   (__attribute__((address_space(3))) void*)l, 16, 0, 0);
}

DEV bf16x8 cvt8f(f32x4 a, f32x4 b) {
  union { bf16 t[8]; bf16x8 v; } u;
  u.t[0] = (bf16)a[0]; u.t[1] = (bf16)a[1]; u.t[2] = (bf16)a[2]; u.t[3] = (bf16)a[3];
  u.t[4] = (bf16)b[0]; u.t[5] = (bf16)b[1]; u.t[6] = (bf16)b[2]; u.t[7] = (bf16)b[3];
  return u.v;
}

__global__ void k_initx(const float* __restrict__ s, float* __restrict__ xf,
                        bf16* __restrict__ xb, int n4) {
  int i = blockIdx.x * blockDim.x + threadIdx.x;
  int st = gridDim.x * blockDim.x;
  for (; i < n4; i += st) {
    float4 v = ((const float4*)s)[i];
    ((float4*)xf)[i] = v;
    union { bf16 t[4]; short4 q; } u;
    u.t[0] = (bf16)v.x; u.t[1] = (bf16)v.y; u.t[2] = (bf16)v.z; u.t[3] = (bf16)v.w;
    ((short4*)xb)[i] = u.q;
  }
}

// ---------------- B^T GEMM, f32 weights staged to f32 LDS via global_load_lds ----------
// C[M,N] = A[M,K](bf16) * W[N,K]^T(f32, cvt at fragment read) + bias.
// 128x128 tile, BK=32, 4 waves (2x2). A: bf16 LDS (16B granule, key (row>>1)&3);
// B: f32 LDS (16B granule = 4 f32, 8 slots/row, key row&7 -> balanced 8 words/bank).
template <int OUT>  // 1: bf16 out, 2: + exact GELU, 3: bf16 out + V-transpose side-write
__global__ __launch_bounds__(256) void k_gemm(const bf16* __restrict__ A,
                                              const float* __restrict__ W,
                                              const float* __restrict__ bias,
                                              void* __restrict__ C,
                                              bf16* __restrict__ vt,
                                              int M, int N, int K) {
  __shared__ alignas(128) bf16 As[2][128 * 32];
  __shared__ alignas(128) float Bsf[2][128 * 32];
  const int tid = threadIdx.x, lane = tid & 63, wave = tid >> 6;
  const int wr = wave >> 1, wc = wave & 1;
  const int bx = blockIdx.x, by = blockIdx.y;
  const bf16* Ab = A + (size_t)by * 128 * K;
  const float* Wb = W + (size_t)bx * 128 * K;
  const int s0 = tid, s1 = tid + 256;
  const int ar0 = s0 >> 2, ac0 = ((s0 & 3) ^ ((ar0 >> 1) & 3)) << 3;
  const int ar1 = s1 >> 2, ac1 = ((s1 & 3) ^ ((ar1 >> 1) & 3)) << 3;

  f32x4 acc[4][4] = {};
  const int KT = K >> 5;
  int cur = 0;
  // prologue stage tile 0
  gld16(Ab + (size_t)ar0 * K + ac0, &As[0][s0 * 8]);
  gld16(Ab + (size_t)ar1 * K + ac1, &As[0][s1 * 8]);
#pragma unroll
  for (int i = 0; i < 4; ++i) {
    int gg = i * 256 + tid;
    int brow = gg >> 3, bslot = gg & 7;
    gld16f(Wb + (size_t)brow * K + ((bslot ^ (brow & 7)) << 2), &Bsf[0][gg * 4]);
  }

  const int r = lane & 15, kg = lane >> 4;
  for (int kt = 0; kt < KT; ++kt) {
    __syncthreads();
    if (kt + 1 < KT) {
      int k0 = (kt + 1) << 5;
      gld16(Ab + (size_t)ar0 * K + k0 + ac0, &As[cur ^ 1][s0 * 8]);
      gld16(Ab + (size_t)ar1 * K + k0 + ac1, &As[cur ^ 1][s1 * 8]);
#pragma unroll
      for (int i = 0; i < 4; ++i) {
        int gg = i * 256 + tid;
        int brow = gg >> 3, bslot = gg & 7;
        gld16f(Wb + (size_t)brow * K + k0 + ((bslot ^ (brow & 7)) << 2),
               &Bsf[cur ^ 1][gg * 4]);
      }
    }
    const bf16* Ac = As[cur];
    const float* Bc = Bsf[cur];
    bf16x8 af[4], bfr[4];
#pragma unroll
    for (int m = 0; m < 4; ++m) {
      int row = wr * 64 + m * 16 + r;
      af[m] = *(const bf16x8*)(Ac + row * 32 + ((kg ^ ((row >> 1) & 3)) << 3));
    }
#pragma unroll
    for (int n = 0; n < 4; ++n) {
      int row = wc * 64 + n * 16 + r;
      int sl0 = (2 * kg) ^ (row & 7), sl1 = (2 * kg + 1) ^ (row & 7);
      f32x4 w0 = *(const f32x4*)(Bc + row * 32 + sl0 * 4);
      f32x4 w1 = *(const f32x4*)(Bc + row * 32 + sl1 * 4);
      bfr[n] = cvt8f(w0, w1);
    }
#pragma unroll
    for (int m = 0; m < 4; ++m)
#pragma unroll
      for (int n = 0; n < 4; ++n)
        acc[m][n] = __builtin_amdgcn_mfma_f32_16x16x32_bf16(af[m], bfr[n], acc[m][n], 0, 0, 0);
    cur ^= 1;
  }
  const int g = lane >> 4, c16 = lane & 15;
#pragma unroll
  for (int m = 0; m < 4; ++m) {
#pragma unroll
    for (int n = 0; n < 4; ++n) {
      int col = bx * 128 + wc * 64 + n * 16 + c16;
      float bv = bias[col];
      if (OUT == 3 && col >= 2 * HDIM) {
        // V columns -> write transposed vT[(b,h),d,s], 4 consecutive s packed
        int hh = (col - 2 * HDIM) >> 6, dd = (col - 2 * HDIM) & 63;
        int row0 = by * 128 + wr * 64 + m * 16 + g * 4;
        int bb_ = row0 >> 9, ss = row0 & 511;
        union { bf16 t[4]; short4 q; } u;
#pragma unroll
        for (int j = 0; j < 4; ++j) u.t[j] = (bf16)(acc[m][n][j] + bv);
        *(short4*)(vt + (((size_t)(bb_ * NHEADS + hh) * DHEAD + dd) * SEQ + ss)) = u.q;
      } else {
#pragma unroll
        for (int j = 0; j < 4; ++j) {
          int row = by * 128 + wr * 64 + m * 16 + g * 4 + j;
          float v = acc[m][n][j] + bv;
          if (OUT == 2) v = 0.5f * v * (1.0f + erff(v * 0.70710678118f));
          ((bf16*)C)[(size_t)row * N + col] = (bf16)v;
        }
      }
    }
  }
}

// ---------------- split-K B^T GEMM, f32 weights, f32 partials [z][M*N] ----------------
__global__ __launch_bounds__(256) void k_gemm_sk(const bf16* __restrict__ A,
                                                 const float* __restrict__ W,
                                                 float* __restrict__ C,
                                                 int M, int N, int Kc, int ld) {
  __shared__ alignas(128) bf16 As[2][128 * 32];
  __shared__ alignas(128) float Bsf[2][128 * 32];
  const int tid = threadIdx.x, lane = tid & 63, wave = tid >> 6;
  const int wr = wave >> 1, wc = wave & 1;
  const int kz = blockIdx.z;
  const bf16* Ab = A + (size_t)blockIdx.y * 128 * ld + (size_t)kz * Kc;
  const float* Wb = W + (size_t)blockIdx.x * 128 * ld + (size_t)kz * Kc;
  float* Cz = C + (size_t)kz * M * N;
  const int s0 = tid, s1 = tid + 256;
  const int ar0 = s0 >> 2, ac0 = ((s0 & 3) ^ ((ar0 >> 1) & 3)) << 3;
  const int ar1 = s1 >> 2, ac1 = ((s1 & 3) ^ ((ar1 >> 1) & 3)) << 3;

  f32x4 acc[4][4] = {};
  const int KT = Kc >> 5;
  int cur = 0;
  gld16(Ab + (size_t)ar0 * ld + ac0, &As[0][s0 * 8]);
  gld16(Ab + (size_t)ar1 * ld + ac1, &As[0][s1 * 8]);
#pragma unroll
  for (int i = 0; i < 4; ++i) {
    int gg = i * 256 + tid;
    int brow = gg >> 3, bslot = gg & 7;
    gld16f(Wb + (size_t)brow * ld + ((bslot ^ (brow & 7)) << 2), &Bsf[0][gg * 4]);
  }

  const int r = lane & 15, kg = lane >> 4;
  for (int kt = 0; kt < KT; ++kt) {
    __syncthreads();
    if (kt + 1 < KT) {
      int k0 = (kt + 1) << 5;
      gld16(Ab + (size_t)ar0 * ld + k0 + ac0, &As[cur ^ 1][s0 * 8]);
      gld16(Ab + (size_t)ar1 * ld + k0 + ac1, &As[cur ^ 1][s1 * 8]);
#pragma unroll
      for (int i = 0; i < 4; ++i) {
        int gg = i * 256 + tid;
        int brow = gg >> 3, bslot = gg & 7;
        gld16f(Wb + (size_t)brow * ld + k0 + ((bslot ^ (brow & 7)) << 2),
               &Bsf[cur ^ 1][gg * 4]);
      }
    }
    const bf16* Ac = As[cur];
    const float* Bc = Bsf[cur];
    bf16x8 af[4], bfr[4];
#pragma unroll
    for (int m = 0; m < 4; ++m) {
      int row = wr * 64 + m * 16 + r;
      af[m] = *(const bf16x8*)(Ac + row * 32 + ((kg ^ ((row >> 1) & 3)) << 3));
    }
#pragma unroll
    for (int n = 0; n < 4; ++n) {
      int row = wc * 64 + n * 16 + r;
      int sl0 = (2 * kg) ^ (row & 7), sl1 = (2 * kg + 1) ^ (row & 7);
      f32x4 w0 = *(const f32x4*)(Bc + row * 32 + sl0 * 4);
      f32x4 w1 = *(const f32x4*)(Bc + row * 32 + sl1 * 4);
      bfr[n] = cvt8f(w0, w1);
    }
#pragma unroll
    for (int m = 0; m < 4; ++m)
#pragma unroll
      for (int n = 0; n < 4; ++n)
        acc[m][n] = __builtin_amdgcn_mfma_f32_16x16x32_bf16(af[m], bfr[n], acc[m][n], 0, 0, 0);
    cur ^= 1;
  }
  const int g = lane >> 4, c16 = lane & 15;
#pragma unroll
  for (int m = 0; m < 4; ++m)
#pragma unroll
    for (int n = 0; n < 4; ++n) {
      int col = blockIdx.x * 128 + wc * 64 + n * 16 + c16;
#pragma unroll
      for (int j = 0; j < 4; ++j) {
        int row = blockIdx.y * 128 + wr * 64 + m * 16 + g * 4 + j;
        Cz[(size_t)row * N + col] = acc[m][n][j];
      }
    }
}

// ---------------- fused attention: scores + softmax + PV -> ctx ----------------
__global__ __launch_bounds__(256) void k_attn(const bf16* __restrict__ qkv,
                                              const bf16* __restrict__ vT,
                                              const float* __restrict__ mask,
                                              bf16* __restrict__ ctx) {
  __shared__ alignas(128) bf16 smem[20480];  // 40 KB
  bf16* Qs = smem;           // [64][64]   phase 1
  bf16* Ks = smem + 4096;    // [256][64]  phase 1
  bf16* Vs = smem;           // [64][256]  phase 2 (aliases Q/K region)
  bf16* Ps = smem + 16384;   // [4][16][32] phase 2
  const int tid = threadIdx.x, lane = tid & 63, wave = tid >> 6;
  const int q0 = blockIdx.x * 64;
  const int h = blockIdx.y, b = blockIdx.z;
  const int bh = b * NHEADS + h;
  const bf16* qbase = qkv + (size_t)(b * SEQ) * H3 + h * DHEAD;
  const bf16* kbase = qbase + HDIM;
  const bf16* Vsrc = vT + (size_t)bh * DHEAD * SEQ;
  const int r15 = lane & 15, kg = lane >> 4;

  for (int s = tid; s < 512; s += 256) {
    int r = s >> 3, sl = s & 7;
    gld16(qbase + (size_t)(q0 + r) * H3 + ((sl ^ (r & 7)) << 3), &Qs[s * 8]);
  }
  f32x4 acc[32];
#pragma unroll
  for (int f = 0; f < 32; ++f) acc[f] = (f32x4){0.f, 0.f, 0.f, 0.f};

  for (int half = 0; half < 2; ++half) {
    for (int s = tid; s < 2048; s += 256) {
      int r = s >> 3, sl = s & 7;
      gld16(kbase + (size_t)(half * 256 + r) * H3 + ((sl ^ (r & 7)) << 3), &Ks[s * 8]);
    }
    __syncthreads();
#pragma unroll
    for (int ks = 0; ks < 2; ++ks) {
      int qrow = wave * 16 + r15;
      int sl = ks * 4 + kg;
      bf16x8 aq = *(const bf16x8*)(Qs + qrow * 64 + ((sl ^ (qrow & 7)) << 3));
#pragma unroll
      for (int nf = 0; nf < 16; ++nf) {
        int krow = nf * 16 + r15;
        bf16x8 bk = *(const bf16x8*)(Ks + krow * 64 + ((sl ^ (krow & 7)) << 3));
        acc[half * 16 + nf] =
            __builtin_amdgcn_mfma_f32_16x16x32_bf16(aq, bk, acc[half * 16 + nf], 0, 0, 0);
      }
    }
    __syncthreads();
  }

  // stage V half 0 into vacated LDS; loads fly during softmax
#pragma unroll
  for (int i = 0; i < 8; ++i) {
    int g16 = tid + i * 256;
    int d = g16 >> 5, c = g16 & 31;
    gld16(Vsrc + (size_t)d * SEQ + ((c ^ (d & 7)) << 3), &Vs[g16 * 8]);
  }

  const float* mrow = mask + b * SEQ;
#pragma unroll
  for (int f = 0; f < 32; ++f) {
    float mv = mrow[f * 16 + r15];
#pragma unroll
    for (int j = 0; j < 4; ++j) acc[f][j] = acc[f][j] * SCALE + mv;
  }
#pragma unroll
  for (int j = 0; j < 4; ++j) {
    float m = -1e30f;
#pragma unroll
    for (int f = 0; f < 32; ++f) m = fmaxf(m, acc[f][j]);
    m = fmaxf(m, __shfl_xor(m, 1));
    m = fmaxf(m, __shfl_xor(m, 2));
    m = fmaxf(m, __shfl_xor(m, 4));
    m = fmaxf(m, __shfl_xor(m, 8));
    float sum = 0.f;
#pragma unroll
    for (int f = 0; f < 32; ++f) { acc[f][j] = __expf(acc[f][j] - m); sum += acc[f][j]; }
    sum += __shfl_xor(sum, 1);
    sum += __shfl_xor(sum, 2);
    sum += __shfl_xor(sum, 4);
    sum += __shfl_xor(sum, 8);
    float inv = 1.0f / sum;
#pragma unroll
    for (int f = 0; f < 32; ++f) acc[f][j] *= inv;
  }
  __syncthreads();  // V half 0 staged

  f32x4 pvacc[4] = {};
  bf16* Pw = Ps + wave * (16 * 32);
#pragma unroll
  for (int half = 0; half < 2; ++half) {
    if (half == 1) {
      __syncthreads();
#pragma unroll
      for (int i = 0; i < 8; ++i) {
        int g16 = tid + i * 256;
        int d = g16 >> 5, c = g16 & 31;
        gld16(Vsrc + (size_t)d * SEQ + 256 + ((c ^ (d & 7)) << 3), &Vs[g16 * 8]);
      }
      __syncthreads();
    }
#pragma unroll
    for (int kc8 = 0; kc8 < 8; ++kc8) {
      int kc = half * 8 + kc8;
#pragma unroll
      for (int fb = 0; fb < 2; ++fb)
#pragma unroll
        for (int j = 0; j < 4; ++j) {
          int q = kg * 4 + j, k = fb * 16 + r15;
          Pw[q * 32 + ((((k >> 3) ^ ((q >> 1) & 3)) << 3) | (k & 7))] =
              (bf16)acc[kc * 2 + fb][j];
        }
      bf16x8 pa = *(const bf16x8*)(Pw + r15 * 32 + ((kg ^ ((r15 >> 1) & 3)) << 3));
#pragma unroll
      for (int n = 0; n < 4; ++n) {
        int d = n * 16 + r15;
        bf16x8 vb = *(const bf16x8*)(Vs + d * 256 + (((kc8 * 4 + kg) ^ (d & 7)) << 3));
        pvacc[n] = __builtin_amdgcn_mfma_f32_16x16x32_bf16(pa, vb, pvacc[n], 0, 0, 0);
      }
    }
  }

  bf16* crow = ctx + (size_t)(b * SEQ + q0 + wave * 16) * HDIM + h * DHEAD;
#pragma unroll
  for (int n = 0; n < 4; ++n)
#pragma unroll
    for (int j = 0; j < 4; ++j)
      crow[(size_t)(kg * 4 + j) * HDIM + n * 16 + r15] = (bf16)pvacc[n][j];
}

// ---------------- residual + 4 split-K partials + bias + LayerNorm ----------------
__global__ __launch_bounds__(256) void k_ln4(const float* __restrict__ x,
                                             const float* __restrict__ d,   // [4][MTOK*HDIM]
                                             const float* __restrict__ bias,
                                             const float* __restrict__ gamma,
                                             const float* __restrict__ beta,
                                             float* __restrict__ xo, bf16* __restrict__ xb) {
  const size_t MH = (size_t)MTOK * HDIM;
  int row = blockIdx.x;
  const float* xr = x + (size_t)row * HDIM;
  const float* dr = d + (size_t)row * HDIM;
  int t = threadIdx.x;
  float v[3];
  float s1 = 0.f, s2 = 0.f;
#pragma unroll
  for (int i = 0; i < 3; ++i) {
    int c = i * 256 + t;
    float a = xr[c] + bias[c] + dr[c] + dr[c + MH] + dr[c + 2 * MH] + dr[c + 3 * MH];
    v[i] = a; s1 += a; s2 += a * a;
  }
#pragma unroll
  for (int o = 32; o; o >>= 1) { s1 += __shfl_down(s1, o); s2 += __shfl_down(s2, o); }
  __shared__ float red[8];
  int wv = t >> 6, lane = t & 63;
  if (lane == 0) { red[wv] = s1; red[4 + wv] = s2; }
  __syncthreads();
  s1 = red[0] + red[1] + red[2] + red[3];
  s2 = red[4] + red[5] + red[6] + red[7];
  float mean = s1 * (1.0f / 768.0f);
  float var = s2 * (1.0f / 768.0f) - mean * mean;
  float rs = rsqrtf(var + 1e-12f);
  float* xro = xo + (size_t)row * HDIM;
  bf16* xbr = xb + (size_t)row * HDIM;
#pragma unroll
  for (int i = 0; i < 3; ++i) {
    int c = i * 256 + t;
    float o = (v[i] - mean) * rs * gamma[c] + beta[c];
    xro[c] = o; xbr[c] = (bf16)o;
  }
}

// ---------------- host orchestration ----------------
extern "C" void kernel_launch(void* const* d_in, const int* in_sizes, int n_in,
                              void* d_out, int out_size, void* d_ws, size_t ws_size,
                              hipStream_t stream) {
  const float* hidden = (const float*)d_in[0];
  const float* mask   = (const float*)d_in[1];
  const float* nAg    = (const float*)d_in[2];
  const float* nAb    = (const float*)d_in[3];
  const float* nBg    = (const float*)d_in[4];
  const float* nBb    = (const float*)d_in[5];
  const float* wa     = (const float*)d_in[6];
  const float* ba     = (const float*)d_in[7];
  const float* wb     = (const float*)d_in[8];
  const float* bb     = (const float*)d_in[9];
  const float* wc     = (const float*)d_in[10];
  const float* bc     = (const float*)d_in[11];
  const float* wd     = (const float*)d_in[12];
  const float* bd     = (const float*)d_in[13];

  char* p = (char*)d_ws;
  auto alloc = [&](size_t bytes) {
    char* r = p;
    p += (bytes + 255) & ~(size_t)255;
    return (void*)r;
  };
  float* xf   = (float*)alloc((size_t)MTOK * HDIM * 4);
  bf16* xb    = (bf16*)alloc((size_t)MTOK * HDIM * 2);
  bf16* qkv   = (bf16*)alloc((size_t)MTOK * H3 * 2);
  bf16* vT    = (bf16*)alloc((size_t)BATCH * NHEADS * DHEAD * SEQ * 2);
  bf16* ctx   = (bf16*)alloc((size_t)MTOK * HDIM * 2);
  bf16* hbuf  = (bf16*)alloc((size_t)MTOK * IDIM * 2);
  float* dres = (float*)alloc((size_t)4 * MTOK * HDIM * 4);  // 4 split-K partials

  k_initx<<<1024, 256, 0, stream>>>(hidden, xf, xb, MTOK * HDIM / 4);

  for (int l = 0; l < 12; ++l) {
    const float* waL = wa + (size_t)l * H3 * HDIM;
    const float* wbL = wb + (size_t)l * HDIM * HDIM;
    const float* wcL = wc + (size_t)l * IDIM * HDIM;
    const float* wdL = wd + (size_t)l * HDIM * IDIM;

    // QKV GEMM: writes Q,K rows to qkv; V columns transposed straight to vT
    k_gemm<3><<<dim3(H3 / 128, MTOK / 128), 256, 0, stream>>>(
        xb, waL, ba + (size_t)l * H3, qkv, vT, MTOK, H3, HDIM);
    k_attn<<<dim3(SEQ / 64, NHEADS, BATCH), 256, 0, stream>>>(qkv, vT, mask, ctx);
    // attn proj: split-K4 (Kc=192), partials -> dres
    k_gemm_sk<<<dim3(HDIM / 128, MTOK / 128, 4), 256, 0, stream>>>(
        ctx, wbL, dres, MTOK, HDIM, HDIM / 4, HDIM);
    k_ln4<<<MTOK, 256, 0, stream>>>(xf, dres, bb + (size_t)l * HDIM,
                                    nAg + (size_t)l * HDIM, nAb + (size_t)l * HDIM, xf, xb);
    // FFN1 + exact GELU -> hbuf (bf16), bias fused
    k_gemm<2><<<dim3(IDIM / 128, MTOK / 128), 256, 0, stream>>>(
        xb, wcL, bc + (size_t)l * IDIM, hbuf, nullptr, MTOK, IDIM, HDIM);
    // FFN2: split-K4 (Kc=768), partials -> dres
    k_gemm_sk<<<dim3(HDIM / 128, MTOK / 128, 4), 256, 0, stream>>>(
        hbuf, wdL, dres, MTOK, HDIM, IDIM / 4, IDIM);
    float* xout = (l == 11) ? (float*)d_out : xf;
    k_ln4<<<MTOK, 256, 0, stream>>>(xf, dres, bd + (size_t)l * HDIM,
                                    nBg + (size_t)l * HDIM, nBb + (size_t)l * HDIM, xout, xb);
  }
}

// Round 6
// 2145.203 us; speedup vs baseline: 1.1190x; 1.1190x over previous
//
#include <hip/hip_runtime.h>
#include <hip/hip_bf16.h>
#include <cmath>

typedef __bf16 bf16;
typedef __attribute__((ext_vector_type(8))) __bf16 bf16x8;
typedef __attribute__((ext_vector_type(4))) float f32x4;

#define DEV __device__ __forceinline__

constexpr int HDIM = 768, NHEADS = 12, DHEAD = 64, IDIM = 3072, BATCH = 8, SEQ = 512;
constexpr int MTOK = BATCH * SEQ;   // 4096 tokens
constexpr int H3 = 3 * HDIM;        // 2304
constexpr float SCALE = 0.125f;     // 1/sqrt(64)

DEV void gld16(const bf16* g, bf16* l) {
  __builtin_amdgcn_global_load_lds((const __attribute__((address_space(1))) void*)g,
                                   (__attribute__((address_space(3))) void*)l, 16, 0, 0);
}

// ---------------- weight conversion: all four tensors, grid-stride, float4 ----------------
__global__ void k_cvt_all(const float* __restrict__ a, const float* __restrict__ b,
                          const float* __restrict__ c, const float* __restrict__ d,
                          bf16* __restrict__ oa, bf16* __restrict__ ob,
                          bf16* __restrict__ oc, bf16* __restrict__ od,
                          long na, long nb, long nc, long nd) {
  long i0 = ((long)blockIdx.x * blockDim.x + threadIdx.x) * 4;
  long st = (long)gridDim.x * blockDim.x * 4;
  union U { bf16 t[4]; short4 s; };
  for (long i = i0; i < na; i += st) {
    float4 v = *(const float4*)(a + i);
    U u; u.t[0] = (bf16)v.x; u.t[1] = (bf16)v.y; u.t[2] = (bf16)v.z; u.t[3] = (bf16)v.w;
    *(short4*)(oa + i) = u.s;
  }
  for (long i = i0; i < nb; i += st) {
    float4 v = *(const float4*)(b + i);
    U u; u.t[0] = (bf16)v.x; u.t[1] = (bf16)v.y; u.t[2] = (bf16)v.z; u.t[3] = (bf16)v.w;
    *(short4*)(ob + i) = u.s;
  }
  for (long i = i0; i < nc; i += st) {
    float4 v = *(const float4*)(c + i);
    U u; u.t[0] = (bf16)v.x; u.t[1] = (bf16)v.y; u.t[2] = (bf16)v.z; u.t[3] = (bf16)v.w;
    *(short4*)(oc + i) = u.s;
  }
  for (long i = i0; i < nd; i += st) {
    float4 v = *(const float4*)(d + i);
    U u; u.t[0] = (bf16)v.x; u.t[1] = (bf16)v.y; u.t[2] = (bf16)v.z; u.t[3] = (bf16)v.w;
    *(short4*)(od + i) = u.s;
  }
}

__global__ void k_initx(const float* __restrict__ s, float* __restrict__ xf,
                        bf16* __restrict__ xb, int n4) {
  int i = blockIdx.x * blockDim.x + threadIdx.x;
  int st = gridDim.x * blockDim.x;
  for (; i < n4; i += st) {
    float4 v = ((const float4*)s)[i];
    ((float4*)xf)[i] = v;
    union { bf16 t[4]; short4 q; } u;
    u.t[0] = (bf16)v.x; u.t[1] = (bf16)v.y; u.t[2] = (bf16)v.z; u.t[3] = (bf16)v.w;
    ((short4*)xb)[i] = u.q;
  }
}

// ---------------- B^T GEMM (full K): C[M,N] = A[M,K] * W[N,K]^T + bias ----------------
// 128x128 tile, BK=32, 4 waves (2x2), both operands bf16 via global_load_lds
// (linear dest, pre-swizzled source, key (row>>1)&3 -> ~2-way LDS conflicts).
template <int OUT>  // 1: bf16 out, 2: + exact GELU, 3: bf16 out + V-transpose side-write
__global__ __launch_bounds__(256) void k_gemm(const bf16* __restrict__ A,
                                              const bf16* __restrict__ W,
                                              const float* __restrict__ bias,
                                              void* __restrict__ C,
                                              bf16* __restrict__ vt,
                                              int M, int N, int K) {
  __shared__ alignas(128) bf16 As[2][128 * 32];
  __shared__ alignas(128) bf16 Bs[2][128 * 32];
  const int tid = threadIdx.x;
  const int lane = tid & 63, wave = tid >> 6;
  const int wr = wave >> 1, wc = wave & 1;
  const int bx = blockIdx.x, by = blockIdx.y;
  const bf16* Ab = A + (size_t)by * 128 * K;
  const bf16* Bb = W + (size_t)bx * 128 * K;
  const int s0 = tid, s1 = tid + 256;
  const int r0 = s0 >> 2, c0 = ((s0 & 3) ^ ((r0 >> 1) & 3)) << 3;
  const int r1 = s1 >> 2, c1 = ((s1 & 3) ^ ((r1 >> 1) & 3)) << 3;

  f32x4 acc[4][4] = {};
  const int KT = K >> 5;
  int cur = 0;
  gld16(Ab + (size_t)r0 * K + c0, &As[0][s0 * 8]);
  gld16(Ab + (size_t)r1 * K + c1, &As[0][s1 * 8]);
  gld16(Bb + (size_t)r0 * K + c0, &Bs[0][s0 * 8]);
  gld16(Bb + (size_t)r1 * K + c1, &Bs[0][s1 * 8]);

  const int r = lane & 15, kg = lane >> 4;
  for (int kt = 0; kt < KT; ++kt) {
    __syncthreads();
    if (kt + 1 < KT) {
      int k0 = (kt + 1) << 5;
      gld16(Ab + (size_t)r0 * K + k0 + c0, &As[cur ^ 1][s0 * 8]);
      gld16(Ab + (size_t)r1 * K + k0 + c1, &As[cur ^ 1][s1 * 8]);
      gld16(Bb + (size_t)r0 * K + k0 + c0, &Bs[cur ^ 1][s0 * 8]);
      gld16(Bb + (size_t)r1 * K + k0 + c1, &Bs[cur ^ 1][s1 * 8]);
    }
    const bf16* Ac = As[cur];
    const bf16* Bc = Bs[cur];
    bf16x8 af[4], bfr[4];
#pragma unroll
    for (int m = 0; m < 4; ++m) {
      int row = wr * 64 + m * 16 + r;
      af[m] = *(const bf16x8*)(Ac + row * 32 + ((kg ^ ((row >> 1) & 3)) << 3));
    }
#pragma unroll
    for (int n = 0; n < 4; ++n) {
      int row = wc * 64 + n * 16 + r;
      bfr[n] = *(const bf16x8*)(Bc + row * 32 + ((kg ^ ((row >> 1) & 3)) << 3));
    }
#pragma unroll
    for (int m = 0; m < 4; ++m)
#pragma unroll
      for (int n = 0; n < 4; ++n)
        acc[m][n] = __builtin_amdgcn_mfma_f32_16x16x32_bf16(af[m], bfr[n], acc[m][n], 0, 0, 0);
    cur ^= 1;
  }
  const int g = lane >> 4, c16 = lane & 15;
#pragma unroll
  for (int m = 0; m < 4; ++m) {
#pragma unroll
    for (int n = 0; n < 4; ++n) {
      int col = bx * 128 + wc * 64 + n * 16 + c16;
      float bv = bias[col];
      if (OUT == 3 && col >= 2 * HDIM) {
        // V columns -> write transposed vT[(b,h),d,s], 4 consecutive s packed
        int hh = (col - 2 * HDIM) >> 6, dd = (col - 2 * HDIM) & 63;
        int row0 = by * 128 + wr * 64 + m * 16 + g * 4;
        int bb_ = row0 >> 9, ss = row0 & 511;
        union { bf16 t[4]; short4 q; } u;
#pragma unroll
        for (int j = 0; j < 4; ++j) u.t[j] = (bf16)(acc[m][n][j] + bv);
        *(short4*)(vt + (((size_t)(bb_ * NHEADS + hh) * DHEAD + dd) * SEQ + ss)) = u.q;
      } else {
#pragma unroll
        for (int j = 0; j < 4; ++j) {
          int row = by * 128 + wr * 64 + m * 16 + g * 4 + j;
          float v = acc[m][n][j] + bv;
          if (OUT == 2) v = 0.5f * v * (1.0f + erff(v * 0.70710678118f));
          ((bf16*)C)[(size_t)row * N + col] = (bf16)v;
        }
      }
    }
  }
}

// ---------------- split-K B^T GEMM: bf16 partials C_z[M,N] (summed in k_ln4) ----------
__global__ __launch_bounds__(256) void k_gemm_sk(const bf16* __restrict__ A,
                                                 const bf16* __restrict__ W,
                                                 bf16* __restrict__ C,
                                                 int M, int N, int Kc, int ld) {
  __shared__ alignas(128) bf16 As[2][128 * 32];
  __shared__ alignas(128) bf16 Bs[2][128 * 32];
  const int tid = threadIdx.x;
  const int lane = tid & 63, wave = tid >> 6;
  const int wr = wave >> 1, wc = wave & 1;
  const int bx = blockIdx.x, by = blockIdx.y, kz = blockIdx.z;
  const bf16* Ab = A + (size_t)by * 128 * ld + (size_t)kz * Kc;
  const bf16* Bb = W + (size_t)bx * 128 * ld + (size_t)kz * Kc;
  bf16* Cz = C + (size_t)kz * M * N;
  const int s0 = tid, s1 = tid + 256;
  const int r0 = s0 >> 2, c0 = ((s0 & 3) ^ ((r0 >> 1) & 3)) << 3;
  const int r1 = s1 >> 2, c1 = ((s1 & 3) ^ ((r1 >> 1) & 3)) << 3;

  f32x4 acc[4][4] = {};
  const int KT = Kc >> 5;
  int cur = 0;
  gld16(Ab + (size_t)r0 * ld + c0, &As[0][s0 * 8]);
  gld16(Ab + (size_t)r1 * ld + c1, &As[0][s1 * 8]);
  gld16(Bb + (size_t)r0 * ld + c0, &Bs[0][s0 * 8]);
  gld16(Bb + (size_t)r1 * ld + c1, &Bs[0][s1 * 8]);

  const int r = lane & 15, kg = lane >> 4;
  for (int kt = 0; kt < KT; ++kt) {
    __syncthreads();
    if (kt + 1 < KT) {
      int k0 = (kt + 1) << 5;
      gld16(Ab + (size_t)r0 * ld + k0 + c0, &As[cur ^ 1][s0 * 8]);
      gld16(Ab + (size_t)r1 * ld + k0 + c1, &As[cur ^ 1][s1 * 8]);
      gld16(Bb + (size_t)r0 * ld + k0 + c0, &Bs[cur ^ 1][s0 * 8]);
      gld16(Bb + (size_t)r1 * ld + k0 + c1, &Bs[cur ^ 1][s1 * 8]);
    }
    const bf16* Ac = As[cur];
    const bf16* Bc = Bs[cur];
    bf16x8 af[4], bfr[4];
#pragma unroll
    for (int m = 0; m < 4; ++m) {
      int row = wr * 64 + m * 16 + r;
      af[m] = *(const bf16x8*)(Ac + row * 32 + ((kg ^ ((row >> 1) & 3)) << 3));
    }
#pragma unroll
    for (int n = 0; n < 4; ++n) {
      int row = wc * 64 + n * 16 + r;
      bfr[n] = *(const bf16x8*)(Bc + row * 32 + ((kg ^ ((row >> 1) & 3)) << 3));
    }
#pragma unroll
    for (int m = 0; m < 4; ++m)
#pragma unroll
      for (int n = 0; n < 4; ++n)
        acc[m][n] = __builtin_amdgcn_mfma_f32_16x16x32_bf16(af[m], bfr[n], acc[m][n], 0, 0, 0);
    cur ^= 1;
  }
  const int g = lane >> 4, c16 = lane & 15;
#pragma unroll
  for (int m = 0; m < 4; ++m)
#pragma unroll
    for (int n = 0; n < 4; ++n) {
      int col = bx * 128 + wc * 64 + n * 16 + c16;
#pragma unroll
      for (int j = 0; j < 4; ++j) {
        int row = by * 128 + wr * 64 + m * 16 + g * 4 + j;
        Cz[(size_t)row * N + col] = (bf16)acc[m][n][j];
      }
    }
}

// ---------------- fused attention: scores + softmax + PV -> ctx ----------------
__global__ __launch_bounds__(256) void k_attn(const bf16* __restrict__ qkv,
                                              const bf16* __restrict__ vT,
                                              const float* __restrict__ mask,
                                              bf16* __restrict__ ctx) {
  __shared__ alignas(128) bf16 smem[20480];  // 40 KB
  bf16* Qs = smem;           // [64][64]   phase 1
  bf16* Ks = smem + 4096;    // [256][64]  phase 1
  bf16* Vs = smem;           // [64][256]  phase 2 (aliases Q/K region)
  bf16* Ps = smem + 16384;   // [4][16][32] phase 2
  const int tid = threadIdx.x, lane = tid & 63, wave = tid >> 6;
  const int q0 = blockIdx.x * 64;
  const int h = blockIdx.y, b = blockIdx.z;
  const int bh = b * NHEADS + h;
  const bf16* qbase = qkv + (size_t)(b * SEQ) * H3 + h * DHEAD;
  const bf16* kbase = qbase + HDIM;
  const bf16* Vsrc = vT + (size_t)bh * DHEAD * SEQ;
  const int r15 = lane & 15, kg = lane >> 4;

  for (int s = tid; s < 512; s += 256) {
    int r = s >> 3, sl = s & 7;
    gld16(qbase + (size_t)(q0 + r) * H3 + ((sl ^ (r & 7)) << 3), &Qs[s * 8]);
  }
  f32x4 acc[32];
#pragma unroll
  for (int f = 0; f < 32; ++f) acc[f] = (f32x4){0.f, 0.f, 0.f, 0.f};

  for (int half = 0; half < 2; ++half) {
    for (int s = tid; s < 2048; s += 256) {
      int r = s >> 3, sl = s & 7;
      gld16(kbase + (size_t)(half * 256 + r) * H3 + ((sl ^ (r & 7)) << 3), &Ks[s * 8]);
    }
    __syncthreads();
#pragma unroll
    for (int ks = 0; ks < 2; ++ks) {
      int qrow = wave * 16 + r15;
      int sl = ks * 4 + kg;
      bf16x8 aq = *(const bf16x8*)(Qs + qrow * 64 + ((sl ^ (qrow & 7)) << 3));
#pragma unroll
      for (int nf = 0; nf < 16; ++nf) {
        int krow = nf * 16 + r15;
        bf16x8 bk = *(const bf16x8*)(Ks + krow * 64 + ((sl ^ (krow & 7)) << 3));
        acc[half * 16 + nf] =
            __builtin_amdgcn_mfma_f32_16x16x32_bf16(aq, bk, acc[half * 16 + nf], 0, 0, 0);
      }
    }
    __syncthreads();
  }

  // stage V half 0 into vacated LDS; loads fly during softmax
#pragma unroll
  for (int i = 0; i < 8; ++i) {
    int g16 = tid + i * 256;
    int d = g16 >> 5, c = g16 & 31;
    gld16(Vsrc + (size_t)d * SEQ + ((c ^ (d & 7)) << 3), &Vs[g16 * 8]);
  }

  const float* mrow = mask + b * SEQ;
#pragma unroll
  for (int f = 0; f < 32; ++f) {
    float mv = mrow[f * 16 + r15];
#pragma unroll
    for (int j = 0; j < 4; ++j) acc[f][j] = acc[f][j] * SCALE + mv;
  }
#pragma unroll
  for (int j = 0; j < 4; ++j) {
    float m = -1e30f;
#pragma unroll
    for (int f = 0; f < 32; ++f) m = fmaxf(m, acc[f][j]);
    m = fmaxf(m, __shfl_xor(m, 1));
    m = fmaxf(m, __shfl_xor(m, 2));
    m = fmaxf(m, __shfl_xor(m, 4));
    m = fmaxf(m, __shfl_xor(m, 8));
    float sum = 0.f;
#pragma unroll
    for (int f = 0; f < 32; ++f) { acc[f][j] = __expf(acc[f][j] - m); sum += acc[f][j]; }
    sum += __shfl_xor(sum, 1);
    sum += __shfl_xor(sum, 2);
    sum += __shfl_xor(sum, 4);
    sum += __shfl_xor(sum, 8);
    float inv = 1.0f / sum;
#pragma unroll
    for (int f = 0; f < 32; ++f) acc[f][j] *= inv;
  }
  __syncthreads();  // V half 0 staged

  f32x4 pvacc[4] = {};
  bf16* Pw = Ps + wave * (16 * 32);
#pragma unroll
  for (int half = 0; half < 2; ++half) {
    if (half == 1) {
      __syncthreads();
#pragma unroll
      for (int i = 0; i < 8; ++i) {
        int g16 = tid + i * 256;
        int d = g16 >> 5, c = g16 & 31;
        gld16(Vsrc + (size_t)d * SEQ + 256 + ((c ^ (d & 7)) << 3), &Vs[g16 * 8]);
      }
      __syncthreads();
    }
#pragma unroll
    for (int kc8 = 0; kc8 < 8; ++kc8) {
      int kc = half * 8 + kc8;
#pragma unroll
      for (int fb = 0; fb < 2; ++fb)
#pragma unroll
        for (int j = 0; j < 4; ++j) {
          int q = kg * 4 + j, k = fb * 16 + r15;
          Pw[q * 32 + ((((k >> 3) ^ ((q >> 1) & 3)) << 3) | (k & 7))] =
              (bf16)acc[kc * 2 + fb][j];
        }
      bf16x8 pa = *(const bf16x8*)(Pw + r15 * 32 + ((kg ^ ((r15 >> 1) & 3)) << 3));
#pragma unroll
      for (int n = 0; n < 4; ++n) {
        int d = n * 16 + r15;
        bf16x8 vb = *(const bf16x8*)(Vs + d * 256 + (((kc8 * 4 + kg) ^ (d & 7)) << 3));
        pvacc[n] = __builtin_amdgcn_mfma_f32_16x16x32_bf16(pa, vb, pvacc[n], 0, 0, 0);
      }
    }
  }

  bf16* crow = ctx + (size_t)(b * SEQ + q0 + wave * 16) * HDIM + h * DHEAD;
#pragma unroll
  for (int n = 0; n < 4; ++n)
#pragma unroll
    for (int j = 0; j < 4; ++j)
      crow[(size_t)(kg * 4 + j) * HDIM + n * 16 + r15] = (bf16)pvacc[n][j];
}

// ---------------- residual + 4 bf16 split-K partials + bias + LayerNorm ----------------
__global__ __launch_bounds__(256) void k_ln4(const float* __restrict__ x,
                                             const bf16* __restrict__ d,   // [4][MTOK*HDIM]
                                             const float* __restrict__ bias,
                                             const float* __restrict__ gamma,
                                             const float* __restrict__ beta,
                                             float* __restrict__ xo, bf16* __restrict__ xb) {
  const size_t MH = (size_t)MTOK * HDIM;
  int row = blockIdx.x;
  const float* xr = x + (size_t)row * HDIM;
  const bf16* dr = d + (size_t)row * HDIM;
  int t = threadIdx.x;
  float v[3];
  float s1 = 0.f, s2 = 0.f;
#pragma unroll
  for (int i = 0; i < 3; ++i) {
    int c = i * 256 + t;
    float a = xr[c] + bias[c] + (float)dr[c] + (float)dr[c + MH] +
              (float)dr[c + 2 * MH] + (float)dr[c + 3 * MH];
    v[i] = a; s1 += a; s2 += a * a;
  }
#pragma unroll
  for (int o = 32; o; o >>= 1) { s1 += __shfl_down(s1, o); s2 += __shfl_down(s2, o); }
  __shared__ float red[8];
  int wv = t >> 6, lane = t & 63;
  if (lane == 0) { red[wv] = s1; red[4 + wv] = s2; }
  __syncthreads();
  s1 = red[0] + red[1] + red[2] + red[3];
  s2 = red[4] + red[5] + red[6] + red[7];
  float mean = s1 * (1.0f / 768.0f);
  float var = s2 * (1.0f / 768.0f) - mean * mean;
  float rs = rsqrtf(var + 1e-12f);
  float* xro = xo + (size_t)row * HDIM;
  bf16* xbr = xb + (size_t)row * HDIM;
#pragma unroll
  for (int i = 0; i < 3; ++i) {
    int c = i * 256 + t;
    float o = (v[i] - mean) * rs * gamma[c] + beta[c];
    xro[c] = o; xbr[c] = (bf16)o;
  }
}

// ---------------- host orchestration ----------------
extern "C" void kernel_launch(void* const* d_in, const int* in_sizes, int n_in,
                              void* d_out, int out_size, void* d_ws, size_t ws_size,
                              hipStream_t stream) {
  const float* hidden = (const float*)d_in[0];
  const float* mask   = (const float*)d_in[1];
  const float* nAg    = (const float*)d_in[2];
  const float* nAb    = (const float*)d_in[3];
  const float* nBg    = (const float*)d_in[4];
  const float* nBb    = (const float*)d_in[5];
  const float* wa     = (const float*)d_in[6];
  const float* ba     = (const float*)d_in[7];
  const float* wb     = (const float*)d_in[8];
  const float* bb     = (const float*)d_in[9];
  const float* wc     = (const float*)d_in[10];
  const float* bc     = (const float*)d_in[11];
  const float* wd     = (const float*)d_in[12];
  const float* bd     = (const float*)d_in[13];

  char* p = (char*)d_ws;
  auto alloc = [&](size_t bytes) {
    char* r = p;
    p += (bytes + 255) & ~(size_t)255;
    return (void*)r;
  };
  float* xf   = (float*)alloc((size_t)MTOK * HDIM * 4);
  bf16* xb    = (bf16*)alloc((size_t)MTOK * HDIM * 2);
  bf16* qkv   = (bf16*)alloc((size_t)MTOK * H3 * 2);
  bf16* vT    = (bf16*)alloc((size_t)BATCH * NHEADS * DHEAD * SEQ * 2);
  bf16* ctx   = (bf16*)alloc((size_t)MTOK * HDIM * 2);
  bf16* hbuf  = (bf16*)alloc((size_t)MTOK * IDIM * 2);
  bf16* dres  = (bf16*)alloc((size_t)4 * MTOK * HDIM * 2);  // 4 bf16 split-K partials

  const size_t wa_n = (size_t)12 * H3 * HDIM;
  const size_t wb_n = (size_t)12 * HDIM * HDIM;
  const size_t wc_n = (size_t)12 * IDIM * HDIM;
  const size_t wd_n = (size_t)12 * HDIM * IDIM;
  size_t used = (size_t)(p - (char*)d_ws);
  const bool upfront = ws_size >= used + (wa_n + wb_n + wc_n + wd_n) * 2 + 8192;

  bf16* wab = (bf16*)alloc((upfront ? wa_n : (size_t)H3 * HDIM) * 2);
  bf16* wbb = (bf16*)alloc((upfront ? wb_n : (size_t)HDIM * HDIM) * 2);
  bf16* wcb = (bf16*)alloc((upfront ? wc_n : (size_t)IDIM * HDIM) * 2);
  bf16* wdb = (bf16*)alloc((upfront ? wd_n : (size_t)HDIM * IDIM) * 2);

  k_initx<<<1024, 256, 0, stream>>>(hidden, xf, xb, MTOK * HDIM / 4);
  if (upfront)
    k_cvt_all<<<2048, 256, 0, stream>>>(wa, wb, wc, wd, wab, wbb, wcb, wdb,
                                        (long)wa_n, (long)wb_n, (long)wc_n, (long)wd_n);

  for (int l = 0; l < 12; ++l) {
    bf16* waL = upfront ? wab + (size_t)l * H3 * HDIM : wab;
    bf16* wbL = upfront ? wbb + (size_t)l * HDIM * HDIM : wbb;
    bf16* wcL = upfront ? wcb + (size_t)l * IDIM * HDIM : wcb;
    bf16* wdL = upfront ? wdb + (size_t)l * HDIM * IDIM : wdb;
    if (!upfront)
      k_cvt_all<<<2048, 256, 0, stream>>>(
          wa + (size_t)l * H3 * HDIM, wb + (size_t)l * HDIM * HDIM,
          wc + (size_t)l * IDIM * HDIM, wd + (size_t)l * HDIM * IDIM,
          waL, wbL, wcL, wdL,
          (long)H3 * HDIM, (long)HDIM * HDIM, (long)IDIM * HDIM, (long)HDIM * IDIM);

    // QKV GEMM: Q,K rows -> qkv; V columns transposed straight to vT; bias fused
    k_gemm<3><<<dim3(H3 / 128, MTOK / 128), 256, 0, stream>>>(
        xb, waL, ba + (size_t)l * H3, qkv, vT, MTOK, H3, HDIM);
    k_attn<<<dim3(SEQ / 64, NHEADS, BATCH), 256, 0, stream>>>(qkv, vT, mask, ctx);
    // attn proj: split-K4 (Kc=192), bf16 partials -> dres
    k_gemm_sk<<<dim3(HDIM / 128, MTOK / 128, 4), 256, 0, stream>>>(
        ctx, wbL, dres, MTOK, HDIM, HDIM / 4, HDIM);
    k_ln4<<<MTOK, 256, 0, stream>>>(xf, dres, bb + (size_t)l * HDIM,
                                    nAg + (size_t)l * HDIM, nAb + (size_t)l * HDIM, xf, xb);
    // FFN1 + exact GELU -> hbuf (bf16), bias fused
    k_gemm<2><<<dim3(IDIM / 128, MTOK / 128), 256, 0, stream>>>(
        xb, wcL, bc + (size_t)l * IDIM, hbuf, nullptr, MTOK, IDIM, HDIM);
    // FFN2: split-K4 (Kc=768), bf16 partials -> dres
    k_gemm_sk<<<dim3(HDIM / 128, MTOK / 128, 4), 256, 0, stream>>>(
        hbuf, wdL, dres, MTOK, HDIM, IDIM / 4, IDIM);
    float* xout = (l == 11) ? (float*)d_out : xf;
    k_ln4<<<MTOK, 256, 0, stream>>>(xf, dres, bd + (size_t)l * HDIM,
                                    nBg + (size_t)l * HDIM, nBb + (size_t)l * HDIM, xout, xb);
  }
}

// Round 7
// 2066.537 us; speedup vs baseline: 1.1616x; 1.0381x over previous
//
#include <hip/hip_runtime.h>
#include <hip/hip_bf16.h>
#include <cmath>

typedef __bf16 bf16;
typedef __attribute__((ext_vector_type(8))) __bf16 bf16x8;
typedef __attribute__((ext_vector_type(4))) float f32x4;
typedef __attribute__((ext_vector_type(8))) short s16x8;

#define DEV __device__ __forceinline__

constexpr int HDIM = 768, NHEADS = 12, DHEAD = 64, IDIM = 3072, BATCH = 8, SEQ = 512;
constexpr int MTOK = BATCH * SEQ;   // 4096 tokens
constexpr int H3 = 3 * HDIM;        // 2304
constexpr float SCALE = 0.125f;     // 1/sqrt(64)

DEV void gld16(const bf16* g, bf16* l) {
  __builtin_amdgcn_global_load_lds((const __attribute__((address_space(1))) void*)g,
                                   (__attribute__((address_space(3))) void*)l, 16, 0, 0);
}

// ---------------- weight conversion, one tensor: 8 f32 -> 8 bf16 per iter ----------------
__global__ void k_cvt(const float* __restrict__ s, bf16* __restrict__ o, long n8) {
  long i = (long)blockIdx.x * blockDim.x + threadIdx.x;
  long st = (long)gridDim.x * blockDim.x;
  for (; i < n8; i += st) {
    const float4* p = (const float4*)s + i * 2;
    float4 v0 = p[0], v1 = p[1];
    union { bf16 t[8]; s16x8 v; } u;
    u.t[0] = (bf16)v0.x; u.t[1] = (bf16)v0.y; u.t[2] = (bf16)v0.z; u.t[3] = (bf16)v0.w;
    u.t[4] = (bf16)v1.x; u.t[5] = (bf16)v1.y; u.t[6] = (bf16)v1.z; u.t[7] = (bf16)v1.w;
    *(s16x8*)(o + i * 8) = u.v;
  }
}

// ---------------- init: hidden f32 -> xb bf16 ----------------
__global__ void k_init_xb(const float* __restrict__ s, bf16* __restrict__ xb, long n8) {
  long i = (long)blockIdx.x * blockDim.x + threadIdx.x;
  long st = (long)gridDim.x * blockDim.x;
  for (; i < n8; i += st) {
    const float4* p = (const float4*)s + i * 2;
    float4 v0 = p[0], v1 = p[1];
    union { bf16 t[8]; s16x8 v; } u;
    u.t[0] = (bf16)v0.x; u.t[1] = (bf16)v0.y; u.t[2] = (bf16)v0.z; u.t[3] = (bf16)v0.w;
    u.t[4] = (bf16)v1.x; u.t[5] = (bf16)v1.y; u.t[6] = (bf16)v1.z; u.t[7] = (bf16)v1.w;
    *(s16x8*)(xb + i * 8) = u.v;
  }
}

// ---------------- B^T GEMM (full K): C[M,N] = A[M,K] * W[N,K]^T + bias ----------------
// 128x128 tile, BK=32, 4 waves (2x2), both operands bf16 via global_load_lds
// (linear dest, pre-swizzled source, key (row>>1)&3 -> ~2-way LDS conflicts).
template <int OUT>  // 1: bf16 out, 2: + exact GELU, 3: bf16 out + V-transpose side-write
__global__ __launch_bounds__(256) void k_gemm(const bf16* __restrict__ A,
                                              const bf16* __restrict__ W,
                                              const float* __restrict__ bias,
                                              void* __restrict__ C,
                                              bf16* __restrict__ vt,
                                              int M, int N, int K) {
  __shared__ alignas(128) bf16 As[2][128 * 32];
  __shared__ alignas(128) bf16 Bs[2][128 * 32];
  const int tid = threadIdx.x;
  const int lane = tid & 63, wave = tid >> 6;
  const int wr = wave >> 1, wc = wave & 1;
  const int bx = blockIdx.x, by = blockIdx.y;
  const bf16* Ab = A + (size_t)by * 128 * K;
  const bf16* Bb = W + (size_t)bx * 128 * K;
  const int s0 = tid, s1 = tid + 256;
  const int r0 = s0 >> 2, c0 = ((s0 & 3) ^ ((r0 >> 1) & 3)) << 3;
  const int r1 = s1 >> 2, c1 = ((s1 & 3) ^ ((r1 >> 1) & 3)) << 3;

  f32x4 acc[4][4] = {};
  const int KT = K >> 5;
  int cur = 0;
  gld16(Ab + (size_t)r0 * K + c0, &As[0][s0 * 8]);
  gld16(Ab + (size_t)r1 * K + c1, &As[0][s1 * 8]);
  gld16(Bb + (size_t)r0 * K + c0, &Bs[0][s0 * 8]);
  gld16(Bb + (size_t)r1 * K + c1, &Bs[0][s1 * 8]);

  const int r = lane & 15, kg = lane >> 4;
  for (int kt = 0; kt < KT; ++kt) {
    __syncthreads();
    if (kt + 1 < KT) {
      int k0 = (kt + 1) << 5;
      gld16(Ab + (size_t)r0 * K + k0 + c0, &As[cur ^ 1][s0 * 8]);
      gld16(Ab + (size_t)r1 * K + k0 + c1, &As[cur ^ 1][s1 * 8]);
      gld16(Bb + (size_t)r0 * K + k0 + c0, &Bs[cur ^ 1][s0 * 8]);
      gld16(Bb + (size_t)r1 * K + k0 + c1, &Bs[cur ^ 1][s1 * 8]);
    }
    const bf16* Ac = As[cur];
    const bf16* Bc = Bs[cur];
    bf16x8 af[4], bfr[4];
#pragma unroll
    for (int m = 0; m < 4; ++m) {
      int row = wr * 64 + m * 16 + r;
      af[m] = *(const bf16x8*)(Ac + row * 32 + ((kg ^ ((row >> 1) & 3)) << 3));
    }
#pragma unroll
    for (int n = 0; n < 4; ++n) {
      int row = wc * 64 + n * 16 + r;
      bfr[n] = *(const bf16x8*)(Bc + row * 32 + ((kg ^ ((row >> 1) & 3)) << 3));
    }
#pragma unroll
    for (int m = 0; m < 4; ++m)
#pragma unroll
      for (int n = 0; n < 4; ++n)
        acc[m][n] = __builtin_amdgcn_mfma_f32_16x16x32_bf16(af[m], bfr[n], acc[m][n], 0, 0, 0);
    cur ^= 1;
  }
  const int g = lane >> 4, c16 = lane & 15;
#pragma unroll
  for (int m = 0; m < 4; ++m) {
#pragma unroll
    for (int n = 0; n < 4; ++n) {
      int col = bx * 128 + wc * 64 + n * 16 + c16;
      float bv = bias[col];
      if (OUT == 3 && col >= 2 * HDIM) {
        // V columns -> write transposed vT[(b,h),d,s], 4 consecutive s packed
        int hh = (col - 2 * HDIM) >> 6, dd = (col - 2 * HDIM) & 63;
        int row0 = by * 128 + wr * 64 + m * 16 + g * 4;
        int bb_ = row0 >> 9, ss = row0 & 511;
        union { bf16 t[4]; short4 q; } u;
#pragma unroll
        for (int j = 0; j < 4; ++j) u.t[j] = (bf16)(acc[m][n][j] + bv);
        *(short4*)(vt + (((size_t)(bb_ * NHEADS + hh) * DHEAD + dd) * SEQ + ss)) = u.q;
      } else {
#pragma unroll
        for (int j = 0; j < 4; ++j) {
          int row = by * 128 + wr * 64 + m * 16 + g * 4 + j;
          float v = acc[m][n][j] + bv;
          if (OUT == 2) v = 0.5f * v * (1.0f + erff(v * 0.70710678118f));
          ((bf16*)C)[(size_t)row * N + col] = (bf16)v;
        }
      }
    }
  }
}

// ---------------- split-K B^T GEMM: bf16 partials C_z[M,N] (summed in k_ln4) ----------
__global__ __launch_bounds__(256) void k_gemm_sk(const bf16* __restrict__ A,
                                                 const bf16* __restrict__ W,
                                                 bf16* __restrict__ C,
                                                 int M, int N, int Kc, int ld) {
  __shared__ alignas(128) bf16 As[2][128 * 32];
  __shared__ alignas(128) bf16 Bs[2][128 * 32];
  const int tid = threadIdx.x;
  const int lane = tid & 63, wave = tid >> 6;
  const int wr = wave >> 1, wc = wave & 1;
  const int bx = blockIdx.x, by = blockIdx.y, kz = blockIdx.z;
  const bf16* Ab = A + (size_t)by * 128 * ld + (size_t)kz * Kc;
  const bf16* Bb = W + (size_t)bx * 128 * ld + (size_t)kz * Kc;
  bf16* Cz = C + (size_t)kz * M * N;
  const int s0 = tid, s1 = tid + 256;
  const int r0 = s0 >> 2, c0 = ((s0 & 3) ^ ((r0 >> 1) & 3)) << 3;
  const int r1 = s1 >> 2, c1 = ((s1 & 3) ^ ((r1 >> 1) & 3)) << 3;

  f32x4 acc[4][4] = {};
  const int KT = Kc >> 5;
  int cur = 0;
  gld16(Ab + (size_t)r0 * ld + c0, &As[0][s0 * 8]);
  gld16(Ab + (size_t)r1 * ld + c1, &As[0][s1 * 8]);
  gld16(Bb + (size_t)r0 * ld + c0, &Bs[0][s0 * 8]);
  gld16(Bb + (size_t)r1 * ld + c1, &Bs[0][s1 * 8]);

  const int r = lane & 15, kg = lane >> 4;
  for (int kt = 0; kt < KT; ++kt) {
    __syncthreads();
    if (kt + 1 < KT) {
      int k0 = (kt + 1) << 5;
      gld16(Ab + (size_t)r0 * ld + k0 + c0, &As[cur ^ 1][s0 * 8]);
      gld16(Ab + (size_t)r1 * ld + k0 + c1, &As[cur ^ 1][s1 * 8]);
      gld16(Bb + (size_t)r0 * ld + k0 + c0, &Bs[cur ^ 1][s0 * 8]);
      gld16(Bb + (size_t)r1 * ld + k0 + c1, &Bs[cur ^ 1][s1 * 8]);
    }
    const bf16* Ac = As[cur];
    const bf16* Bc = Bs[cur];
    bf16x8 af[4], bfr[4];
#pragma unroll
    for (int m = 0; m < 4; ++m) {
      int row = wr * 64 + m * 16 + r;
      af[m] = *(const bf16x8*)(Ac + row * 32 + ((kg ^ ((row >> 1) & 3)) << 3));
    }
#pragma unroll
    for (int n = 0; n < 4; ++n) {
      int row = wc * 64 + n * 16 + r;
      bfr[n] = *(const bf16x8*)(Bc + row * 32 + ((kg ^ ((row >> 1) & 3)) << 3));
    }
#pragma unroll
    for (int m = 0; m < 4; ++m)
#pragma unroll
      for (int n = 0; n < 4; ++n)
        acc[m][n] = __builtin_amdgcn_mfma_f32_16x16x32_bf16(af[m], bfr[n], acc[m][n], 0, 0, 0);
    cur ^= 1;
  }
  const int g = lane >> 4, c16 = lane & 15;
#pragma unroll
  for (int m = 0; m < 4; ++m)
#pragma unroll
    for (int n = 0; n < 4; ++n) {
      int col = bx * 128 + wc * 64 + n * 16 + c16;
#pragma unroll
      for (int j = 0; j < 4; ++j) {
        int row = by * 128 + wr * 64 + m * 16 + g * 4 + j;
        Cz[(size_t)row * N + col] = (bf16)acc[m][n][j];
      }
    }
}

// ---------------- fused attention: scores + softmax + PV -> ctx ----------------
__global__ __launch_bounds__(256) void k_attn(const bf16* __restrict__ qkv,
                                              const bf16* __restrict__ vT,
                                              const float* __restrict__ mask,
                                              bf16* __restrict__ ctx) {
  __shared__ alignas(128) bf16 smem[20480];  // 40 KB
  bf16* Qs = smem;           // [64][64]   phase 1
  bf16* Ks = smem + 4096;    // [256][64]  phase 1
  bf16* Vs = smem;           // [64][256]  phase 2 (aliases Q/K region)
  bf16* Ps = smem + 16384;   // [4][16][32] phase 2
  const int tid = threadIdx.x, lane = tid & 63, wave = tid >> 6;
  const int q0 = blockIdx.x * 64;
  const int h = blockIdx.y, b = blockIdx.z;
  const int bh = b * NHEADS + h;
  const bf16* qbase = qkv + (size_t)(b * SEQ) * H3 + h * DHEAD;
  const bf16* kbase = qbase + HDIM;
  const bf16* Vsrc = vT + (size_t)bh * DHEAD * SEQ;
  const int r15 = lane & 15, kg = lane >> 4;

  for (int s = tid; s < 512; s += 256) {
    int r = s >> 3, sl = s & 7;
    gld16(qbase + (size_t)(q0 + r) * H3 + ((sl ^ (r & 7)) << 3), &Qs[s * 8]);
  }
  f32x4 acc[32];
#pragma unroll
  for (int f = 0; f < 32; ++f) acc[f] = (f32x4){0.f, 0.f, 0.f, 0.f};

  for (int half = 0; half < 2; ++half) {
    for (int s = tid; s < 2048; s += 256) {
      int r = s >> 3, sl = s & 7;
      gld16(kbase + (size_t)(half * 256 + r) * H3 + ((sl ^ (r & 7)) << 3), &Ks[s * 8]);
    }
    __syncthreads();
#pragma unroll
    for (int ks = 0; ks < 2; ++ks) {
      int qrow = wave * 16 + r15;
      int sl = ks * 4 + kg;
      bf16x8 aq = *(const bf16x8*)(Qs + qrow * 64 + ((sl ^ (qrow & 7)) << 3));
#pragma unroll
      for (int nf = 0; nf < 16; ++nf) {
        int krow = nf * 16 + r15;
        bf16x8 bk = *(const bf16x8*)(Ks + krow * 64 + ((sl ^ (krow & 7)) << 3));
        acc[half * 16 + nf] =
            __builtin_amdgcn_mfma_f32_16x16x32_bf16(aq, bk, acc[half * 16 + nf], 0, 0, 0);
      }
    }
    __syncthreads();
  }

  // stage V half 0 into vacated LDS; loads fly during softmax
#pragma unroll
  for (int i = 0; i < 8; ++i) {
    int g16 = tid + i * 256;
    int d = g16 >> 5, c = g16 & 31;
    gld16(Vsrc + (size_t)d * SEQ + ((c ^ (d & 7)) << 3), &Vs[g16 * 8]);
  }

  const float* mrow = mask + b * SEQ;
#pragma unroll
  for (int f = 0; f < 32; ++f) {
    float mv = mrow[f * 16 + r15];
#pragma unroll
    for (int j = 0; j < 4; ++j) acc[f][j] = acc[f][j] * SCALE + mv;
  }
#pragma unroll
  for (int j = 0; j < 4; ++j) {
    float m = -1e30f;
#pragma unroll
    for (int f = 0; f < 32; ++f) m = fmaxf(m, acc[f][j]);
    m = fmaxf(m, __shfl_xor(m, 1));
    m = fmaxf(m, __shfl_xor(m, 2));
    m = fmaxf(m, __shfl_xor(m, 4));
    m = fmaxf(m, __shfl_xor(m, 8));
    float sum = 0.f;
#pragma unroll
    for (int f = 0; f < 32; ++f) { acc[f][j] = __expf(acc[f][j] - m); sum += acc[f][j]; }
    sum += __shfl_xor(sum, 1);
    sum += __shfl_xor(sum, 2);
    sum += __shfl_xor(sum, 4);
    sum += __shfl_xor(sum, 8);
    float inv = 1.0f / sum;
#pragma unroll
    for (int f = 0; f < 32; ++f) acc[f][j] *= inv;
  }
  __syncthreads();  // V half 0 staged

  f32x4 pvacc[4] = {};
  bf16* Pw = Ps + wave * (16 * 32);
#pragma unroll
  for (int half = 0; half < 2; ++half) {
    if (half == 1) {
      __syncthreads();
#pragma unroll
      for (int i = 0; i < 8; ++i) {
        int g16 = tid + i * 256;
        int d = g16 >> 5, c = g16 & 31;
        gld16(Vsrc + (size_t)d * SEQ + 256 + ((c ^ (d & 7)) << 3), &Vs[g16 * 8]);
      }
      __syncthreads();
    }
#pragma unroll
    for (int kc8 = 0; kc8 < 8; ++kc8) {
      int kc = half * 8 + kc8;
#pragma unroll
      for (int fb = 0; fb < 2; ++fb)
#pragma unroll
        for (int j = 0; j < 4; ++j) {
          int q = kg * 4 + j, k = fb * 16 + r15;
          Pw[q * 32 + ((((k >> 3) ^ ((q >> 1) & 3)) << 3) | (k & 7))] =
              (bf16)acc[kc * 2 + fb][j];
        }
      bf16x8 pa = *(const bf16x8*)(Pw + r15 * 32 + ((kg ^ ((r15 >> 1) & 3)) << 3));
#pragma unroll
      for (int n = 0; n < 4; ++n) {
        int d = n * 16 + r15;
        bf16x8 vb = *(const bf16x8*)(Vs + d * 256 + (((kc8 * 4 + kg) ^ (d & 7)) << 3));
        pvacc[n] = __builtin_amdgcn_mfma_f32_16x16x32_bf16(pa, vb, pvacc[n], 0, 0, 0);
      }
    }
  }

  bf16* crow = ctx + (size_t)(b * SEQ + q0 + wave * 16) * HDIM + h * DHEAD;
#pragma unroll
  for (int n = 0; n < 4; ++n)
#pragma unroll
    for (int j = 0; j < 4; ++j)
      crow[(size_t)(kg * 4 + j) * HDIM + n * 16 + r15] = (bf16)pvacc[n][j];
}

// ---------------- residual(bf16) + 4 bf16 partials + bias + LayerNorm ----------------
// 192 threads/block (3 waves), 4 cols/thread, fully vectorized loads.
// Writes xo (bf16 residual stream, in-place safe) and optionally fo (f32, final output).
__global__ __launch_bounds__(192) void k_ln4(const bf16* __restrict__ x,
                                             const bf16* __restrict__ d,   // [4][MTOK*HDIM]
                                             const float* __restrict__ bias,
                                             const float* __restrict__ gamma,
                                             const float* __restrict__ beta,
                                             bf16* __restrict__ xo, float* __restrict__ fo) {
  const size_t MH = (size_t)MTOK * HDIM;
  int row = blockIdx.x;
  int t = threadIdx.x;
  int c = t * 4;
  const bf16* xr = x + (size_t)row * HDIM;
  const bf16* dr = d + (size_t)row * HDIM;
  union S4 { bf16 t[4]; short4 s; };
  S4 xv, d0, d1, d2, d3;
  xv.s = *(const short4*)(xr + c);
  d0.s = *(const short4*)(dr + c);
  d1.s = *(const short4*)(dr + MH + c);
  d2.s = *(const short4*)(dr + 2 * MH + c);
  d3.s = *(const short4*)(dr + 3 * MH + c);
  float4 bv = *(const float4*)(bias + c);
  float a[4];
  float s1 = 0.f, s2 = 0.f;
#pragma unroll
  for (int j = 0; j < 4; ++j) {
    float b_ = (j == 0) ? bv.x : (j == 1) ? bv.y : (j == 2) ? bv.z : bv.w;
    a[j] = (float)xv.t[j] + b_ + (float)d0.t[j] + (float)d1.t[j] + (float)d2.t[j] +
           (float)d3.t[j];
    s1 += a[j]; s2 += a[j] * a[j];
  }
#pragma unroll
  for (int o = 32; o; o >>= 1) { s1 += __shfl_down(s1, o); s2 += __shfl_down(s2, o); }
  __shared__ float red[6];
  int wv = t >> 6, lane = t & 63;
  if (lane == 0) { red[wv] = s1; red[3 + wv] = s2; }
  __syncthreads();
  s1 = red[0] + red[1] + red[2];
  s2 = red[3] + red[4] + red[5];
  float mean = s1 * (1.0f / 768.0f);
  float var = s2 * (1.0f / 768.0f) - mean * mean;
  float rs = rsqrtf(var + 1e-12f);
  float4 gv = *(const float4*)(gamma + c);
  float4 btv = *(const float4*)(beta + c);
  float o0 = (a[0] - mean) * rs * gv.x + btv.x;
  float o1 = (a[1] - mean) * rs * gv.y + btv.y;
  float o2 = (a[2] - mean) * rs * gv.z + btv.z;
  float o3 = (a[3] - mean) * rs * gv.w + btv.w;
  S4 ov;
  ov.t[0] = (bf16)o0; ov.t[1] = (bf16)o1; ov.t[2] = (bf16)o2; ov.t[3] = (bf16)o3;
  *(short4*)(xo + (size_t)row * HDIM + c) = ov.s;
  if (fo) {
    float4 f4 = {o0, o1, o2, o3};
    *(float4*)(fo + (size_t)row * HDIM + c) = f4;
  }
}

// ---------------- host orchestration ----------------
extern "C" void kernel_launch(void* const* d_in, const int* in_sizes, int n_in,
                              void* d_out, int out_size, void* d_ws, size_t ws_size,
                              hipStream_t stream) {
  const float* hidden = (const float*)d_in[0];
  const float* mask   = (const float*)d_in[1];
  const float* nAg    = (const float*)d_in[2];
  const float* nAb    = (const float*)d_in[3];
  const float* nBg    = (const float*)d_in[4];
  const float* nBb    = (const float*)d_in[5];
  const float* wa     = (const float*)d_in[6];
  const float* ba     = (const float*)d_in[7];
  const float* wb     = (const float*)d_in[8];
  const float* bb     = (const float*)d_in[9];
  const float* wc     = (const float*)d_in[10];
  const float* bc     = (const float*)d_in[11];
  const float* wd     = (const float*)d_in[12];
  const float* bd     = (const float*)d_in[13];

  char* p = (char*)d_ws;
  auto alloc = [&](size_t bytes) {
    char* r = p;
    p += (bytes + 255) & ~(size_t)255;
    return (void*)r;
  };
  bf16* xb    = (bf16*)alloc((size_t)MTOK * HDIM * 2);   // bf16 residual stream
  bf16* qkv   = (bf16*)alloc((size_t)MTOK * H3 * 2);
  bf16* vT    = (bf16*)alloc((size_t)BATCH * NHEADS * DHEAD * SEQ * 2);
  bf16* ctx   = (bf16*)alloc((size_t)MTOK * HDIM * 2);
  bf16* hbuf  = (bf16*)alloc((size_t)MTOK * IDIM * 2);
  bf16* dres  = (bf16*)alloc((size_t)4 * MTOK * HDIM * 2);  // 4 bf16 split-K partials

  const size_t wa_n = (size_t)12 * H3 * HDIM;
  const size_t wb_n = (size_t)12 * HDIM * HDIM;
  const size_t wc_n = (size_t)12 * IDIM * HDIM;
  const size_t wd_n = (size_t)12 * HDIM * IDIM;
  size_t used = (size_t)(p - (char*)d_ws);
  const bool upfront = ws_size >= used + (wa_n + wb_n + wc_n + wd_n) * 2 + 8192;

  bf16* wab = (bf16*)alloc((upfront ? wa_n : (size_t)H3 * HDIM) * 2);
  bf16* wbb = (bf16*)alloc((upfront ? wb_n : (size_t)HDIM * HDIM) * 2);
  bf16* wcb = (bf16*)alloc((upfront ? wc_n : (size_t)IDIM * HDIM) * 2);
  bf16* wdb = (bf16*)alloc((upfront ? wd_n : (size_t)HDIM * IDIM) * 2);

  k_init_xb<<<1024, 256, 0, stream>>>(hidden, xb, (long)MTOK * HDIM / 8);
  if (upfront) {
    k_cvt<<<2048, 256, 0, stream>>>(wa, wab, (long)(wa_n / 8));
    k_cvt<<<2048, 256, 0, stream>>>(wb, wbb, (long)(wb_n / 8));
    k_cvt<<<2048, 256, 0, stream>>>(wc, wcb, (long)(wc_n / 8));
    k_cvt<<<2048, 256, 0, stream>>>(wd, wdb, (long)(wd_n / 8));
  }

  for (int l = 0; l < 12; ++l) {
    bf16* waL = upfront ? wab + (size_t)l * H3 * HDIM : wab;
    bf16* wbL = upfront ? wbb + (size_t)l * HDIM * HDIM : wbb;
    bf16* wcL = upfront ? wcb + (size_t)l * IDIM * HDIM : wcb;
    bf16* wdL = upfront ? wdb + (size_t)l * HDIM * IDIM : wdb;
    if (!upfront) {
      k_cvt<<<2048, 256, 0, stream>>>(wa + (size_t)l * H3 * HDIM, waL, (long)(H3 * HDIM / 8));
      k_cvt<<<2048, 256, 0, stream>>>(wb + (size_t)l * HDIM * HDIM, wbL, (long)(HDIM * HDIM / 8));
      k_cvt<<<2048, 256, 0, stream>>>(wc + (size_t)l * IDIM * HDIM, wcL, (long)(IDIM * HDIM / 8));
      k_cvt<<<2048, 256, 0, stream>>>(wd + (size_t)l * HDIM * IDIM, wdL, (long)(HDIM * IDIM / 8));
    }

    // QKV GEMM: Q,K rows -> qkv; V columns transposed straight to vT; bias fused
    k_gemm<3><<<dim3(H3 / 128, MTOK / 128), 256, 0, stream>>>(
        xb, waL, ba + (size_t)l * H3, qkv, vT, MTOK, H3, HDIM);
    k_attn<<<dim3(SEQ / 64, NHEADS, BATCH), 256, 0, stream>>>(qkv, vT, mask, ctx);
    // attn proj: split-K4 (Kc=192), bf16 partials -> dres
    k_gemm_sk<<<dim3(HDIM / 128, MTOK / 128, 4), 256, 0, stream>>>(
        ctx, wbL, dres, MTOK, HDIM, HDIM / 4, HDIM);
    k_ln4<<<MTOK, 192, 0, stream>>>(xb, dres, bb + (size_t)l * HDIM,
                                    nAg + (size_t)l * HDIM, nAb + (size_t)l * HDIM,
                                    xb, nullptr);
    // FFN1 + exact GELU -> hbuf (bf16), bias fused
    k_gemm<2><<<dim3(IDIM / 128, MTOK / 128), 256, 0, stream>>>(
        xb, wcL, bc + (size_t)l * IDIM, hbuf, nullptr, MTOK, IDIM, HDIM);
    // FFN2: split-K4 (Kc=768), bf16 partials -> dres
    k_gemm_sk<<<dim3(HDIM / 128, MTOK / 128, 4), 256, 0, stream>>>(
        hbuf, wdL, dres, MTOK, HDIM, IDIM / 4, IDIM);
    k_ln4<<<MTOK, 192, 0, stream>>>(xb, dres, bd + (size_t)l * HDIM,
                                    nBg + (size_t)l * HDIM, nBb + (size_t)l * HDIM,
                                    xb, (l == 11) ? (float*)d_out : nullptr);
  }
}

// Round 8
// 1900.011 us; speedup vs baseline: 1.2634x; 1.0876x over previous
//
#include <hip/hip_runtime.h>
#include <hip/hip_bf16.h>
#include <cmath>

typedef __bf16 bf16;
typedef __attribute__((ext_vector_type(8))) __bf16 bf16x8;
typedef __attribute__((ext_vector_type(4))) float f32x4;
typedef __attribute__((ext_vector_type(8))) short s16x8;

#define DEV __device__ __forceinline__

constexpr int HDIM = 768, NHEADS = 12, DHEAD = 64, IDIM = 3072, BATCH = 8, SEQ = 512;
constexpr int MTOK = BATCH * SEQ;   // 4096 tokens
constexpr int H3 = 3 * HDIM;        // 2304
constexpr float SCALE = 0.125f;     // 1/sqrt(64)

DEV void gld16(const bf16* g, bf16* l) {
  __builtin_amdgcn_global_load_lds((const __attribute__((address_space(1))) void*)g,
                                   (__attribute__((address_space(3))) void*)l, 16, 0, 0);
}

// ---------------- weight conversion, one tensor: 8 f32 -> 8 bf16 per iter ----------------
__global__ void k_cvt(const float* __restrict__ s, bf16* __restrict__ o, long n8) {
  long i = (long)blockIdx.x * blockDim.x + threadIdx.x;
  long st = (long)gridDim.x * blockDim.x;
  for (; i < n8; i += st) {
    const float4* p = (const float4*)s + i * 2;
    float4 v0 = p[0], v1 = p[1];
    union { bf16 t[8]; s16x8 v; } u;
    u.t[0] = (bf16)v0.x; u.t[1] = (bf16)v0.y; u.t[2] = (bf16)v0.z; u.t[3] = (bf16)v0.w;
    u.t[4] = (bf16)v1.x; u.t[5] = (bf16)v1.y; u.t[6] = (bf16)v1.z; u.t[7] = (bf16)v1.w;
    *(s16x8*)(o + i * 8) = u.v;
  }
}

// ---------------- init: hidden f32 -> xb bf16 ----------------
__global__ void k_init_xb(const float* __restrict__ s, bf16* __restrict__ xb, long n8) {
  long i = (long)blockIdx.x * blockDim.x + threadIdx.x;
  long st = (long)gridDim.x * blockDim.x;
  for (; i < n8; i += st) {
    const float4* p = (const float4*)s + i * 2;
    float4 v0 = p[0], v1 = p[1];
    union { bf16 t[8]; s16x8 v; } u;
    u.t[0] = (bf16)v0.x; u.t[1] = (bf16)v0.y; u.t[2] = (bf16)v0.z; u.t[3] = (bf16)v0.w;
    u.t[4] = (bf16)v1.x; u.t[5] = (bf16)v1.y; u.t[6] = (bf16)v1.z; u.t[7] = (bf16)v1.w;
    *(s16x8*)(xb + i * 8) = u.v;
  }
}

// XCD-aware bijective remap: orig%8 = XCD (round-robin) -> contiguous tile chunk per XCD.
template <int NWG>
DEV int xcd_swz(int id) {
  static_assert(NWG % 8 == 0, "bijective swizzle needs nwg %% 8 == 0");
  return (id & 7) * (NWG / 8) + (id >> 3);
}

// ---------------- B^T GEMM (full K): C[M,N] = A[M,K] * W[N,K]^T + bias ----------------
// 128x128 tile, BK=32, 4 waves (2x2), both operands bf16 via global_load_lds
// (linear dest, pre-swizzled source, key (row>>1)&3 -> ~2-way LDS conflicts).
template <int OUT, int GX, int GY>  // OUT 1: bf16, 2: +GELU, 3: bf16 + V-transpose side-write
__global__ __launch_bounds__(256) void k_gemm(const bf16* __restrict__ A,
                                              const bf16* __restrict__ W,
                                              const float* __restrict__ bias,
                                              void* __restrict__ C,
                                              bf16* __restrict__ vt,
                                              int M, int N, int K) {
  __shared__ alignas(128) bf16 As[2][128 * 32];
  __shared__ alignas(128) bf16 Bs[2][128 * 32];
  const int tid = threadIdx.x;
  const int lane = tid & 63, wave = tid >> 6;
  const int wr = wave >> 1, wc = wave & 1;
  int id = xcd_swz<GX * GY>(blockIdx.x + GX * blockIdx.y);
  const int bx = id % GX, by = id / GX;
  const bf16* Ab = A + (size_t)by * 128 * K;
  const bf16* Bb = W + (size_t)bx * 128 * K;
  const int s0 = tid, s1 = tid + 256;
  const int r0 = s0 >> 2, c0 = ((s0 & 3) ^ ((r0 >> 1) & 3)) << 3;
  const int r1 = s1 >> 2, c1 = ((s1 & 3) ^ ((r1 >> 1) & 3)) << 3;

  f32x4 acc[4][4] = {};
  const int KT = K >> 5;
  int cur = 0;
  gld16(Ab + (size_t)r0 * K + c0, &As[0][s0 * 8]);
  gld16(Ab + (size_t)r1 * K + c1, &As[0][s1 * 8]);
  gld16(Bb + (size_t)r0 * K + c0, &Bs[0][s0 * 8]);
  gld16(Bb + (size_t)r1 * K + c1, &Bs[0][s1 * 8]);

  const int r = lane & 15, kg = lane >> 4;
  for (int kt = 0; kt < KT; ++kt) {
    __syncthreads();
    if (kt + 1 < KT) {
      int k0 = (kt + 1) << 5;
      gld16(Ab + (size_t)r0 * K + k0 + c0, &As[cur ^ 1][s0 * 8]);
      gld16(Ab + (size_t)r1 * K + k0 + c1, &As[cur ^ 1][s1 * 8]);
      gld16(Bb + (size_t)r0 * K + k0 + c0, &Bs[cur ^ 1][s0 * 8]);
      gld16(Bb + (size_t)r1 * K + k0 + c1, &Bs[cur ^ 1][s1 * 8]);
    }
    const bf16* Ac = As[cur];
    const bf16* Bc = Bs[cur];
    bf16x8 af[4], bfr[4];
#pragma unroll
    for (int m = 0; m < 4; ++m) {
      int row = wr * 64 + m * 16 + r;
      af[m] = *(const bf16x8*)(Ac + row * 32 + ((kg ^ ((row >> 1) & 3)) << 3));
    }
#pragma unroll
    for (int n = 0; n < 4; ++n) {
      int row = wc * 64 + n * 16 + r;
      bfr[n] = *(const bf16x8*)(Bc + row * 32 + ((kg ^ ((row >> 1) & 3)) << 3));
    }
#pragma unroll
    for (int m = 0; m < 4; ++m)
#pragma unroll
      for (int n = 0; n < 4; ++n)
        acc[m][n] = __builtin_amdgcn_mfma_f32_16x16x32_bf16(af[m], bfr[n], acc[m][n], 0, 0, 0);
    cur ^= 1;
  }
  const int g = lane >> 4, c16 = lane & 15;
#pragma unroll
  for (int m = 0; m < 4; ++m) {
#pragma unroll
    for (int n = 0; n < 4; ++n) {
      int col = bx * 128 + wc * 64 + n * 16 + c16;
      float bv = bias[col];
      if (OUT == 3 && col >= 2 * HDIM) {
        // V columns -> write transposed vT[(b,h),d,s], 4 consecutive s packed
        int hh = (col - 2 * HDIM) >> 6, dd = (col - 2 * HDIM) & 63;
        int row0 = by * 128 + wr * 64 + m * 16 + g * 4;
        int bb_ = row0 >> 9, ss = row0 & 511;
        union { bf16 t[4]; short4 q; } u;
#pragma unroll
        for (int j = 0; j < 4; ++j) u.t[j] = (bf16)(acc[m][n][j] + bv);
        *(short4*)(vt + (((size_t)(bb_ * NHEADS + hh) * DHEAD + dd) * SEQ + ss)) = u.q;
      } else {
#pragma unroll
        for (int j = 0; j < 4; ++j) {
          int row = by * 128 + wr * 64 + m * 16 + g * 4 + j;
          float v = acc[m][n][j] + bv;
          if (OUT == 2) v = 0.5f * v * (1.0f + erff(v * 0.70710678118f));
          ((bf16*)C)[(size_t)row * N + col] = (bf16)v;
        }
      }
    }
  }
}

// ---------------- split-K B^T GEMM: bf16 partials C_z[M,N] (summed in k_ln4) ----------
template <int GX, int GY, int GZ>
__global__ __launch_bounds__(256) void k_gemm_sk(const bf16* __restrict__ A,
                                                 const bf16* __restrict__ W,
                                                 bf16* __restrict__ C,
                                                 int M, int N, int Kc, int ld) {
  __shared__ alignas(128) bf16 As[2][128 * 32];
  __shared__ alignas(128) bf16 Bs[2][128 * 32];
  const int tid = threadIdx.x;
  const int lane = tid & 63, wave = tid >> 6;
  const int wr = wave >> 1, wc = wave & 1;
  int id = xcd_swz<GX * GY * GZ>(blockIdx.x + GX * (blockIdx.y + GY * blockIdx.z));
  const int bx = id % GX;
  const int t2 = id / GX;
  const int by = t2 % GY, kz = t2 / GY;
  const bf16* Ab = A + (size_t)by * 128 * ld + (size_t)kz * Kc;
  const bf16* Bb = W + (size_t)bx * 128 * ld + (size_t)kz * Kc;
  bf16* Cz = C + (size_t)kz * M * N;
  const int s0 = tid, s1 = tid + 256;
  const int r0 = s0 >> 2, c0 = ((s0 & 3) ^ ((r0 >> 1) & 3)) << 3;
  const int r1 = s1 >> 2, c1 = ((s1 & 3) ^ ((r1 >> 1) & 3)) << 3;

  f32x4 acc[4][4] = {};
  const int KT = Kc >> 5;
  int cur = 0;
  gld16(Ab + (size_t)r0 * ld + c0, &As[0][s0 * 8]);
  gld16(Ab + (size_t)r1 * ld + c1, &As[0][s1 * 8]);
  gld16(Bb + (size_t)r0 * ld + c0, &Bs[0][s0 * 8]);
  gld16(Bb + (size_t)r1 * ld + c1, &Bs[0][s1 * 8]);

  const int r = lane & 15, kg = lane >> 4;
  for (int kt = 0; kt < KT; ++kt) {
    __syncthreads();
    if (kt + 1 < KT) {
      int k0 = (kt + 1) << 5;
      gld16(Ab + (size_t)r0 * ld + k0 + c0, &As[cur ^ 1][s0 * 8]);
      gld16(Ab + (size_t)r1 * ld + k0 + c1, &As[cur ^ 1][s1 * 8]);
      gld16(Bb + (size_t)r0 * ld + k0 + c0, &Bs[cur ^ 1][s0 * 8]);
      gld16(Bb + (size_t)r1 * ld + k0 + c1, &Bs[cur ^ 1][s1 * 8]);
    }
    const bf16* Ac = As[cur];
    const bf16* Bc = Bs[cur];
    bf16x8 af[4], bfr[4];
#pragma unroll
    for (int m = 0; m < 4; ++m) {
      int row = wr * 64 + m * 16 + r;
      af[m] = *(const bf16x8*)(Ac + row * 32 + ((kg ^ ((row >> 1) & 3)) << 3));
    }
#pragma unroll
    for (int n = 0; n < 4; ++n) {
      int row = wc * 64 + n * 16 + r;
      bfr[n] = *(const bf16x8*)(Bc + row * 32 + ((kg ^ ((row >> 1) & 3)) << 3));
    }
#pragma unroll
    for (int m = 0; m < 4; ++m)
#pragma unroll
      for (int n = 0; n < 4; ++n)
        acc[m][n] = __builtin_amdgcn_mfma_f32_16x16x32_bf16(af[m], bfr[n], acc[m][n], 0, 0, 0);
    cur ^= 1;
  }
  const int g = lane >> 4, c16 = lane & 15;
#pragma unroll
  for (int m = 0; m < 4; ++m)
#pragma unroll
    for (int n = 0; n < 4; ++n) {
      int col = bx * 128 + wc * 64 + n * 16 + c16;
#pragma unroll
      for (int j = 0; j < 4; ++j) {
        int row = by * 128 + wr * 64 + m * 16 + g * 4 + j;
        Cz[(size_t)row * N + col] = (bf16)acc[m][n][j];
      }
    }
}

// ---------------- fused attention: scores + softmax + PV -> ctx ----------------
// grid linear 768 = 8 q-tiles x 12 heads x 8 batches; swizzled so the 8 q-tiles of one
// (b,h) (which share 128KB of K/V) land on one XCD's L2.
__global__ __launch_bounds__(256) void k_attn(const bf16* __restrict__ qkv,
                                              const bf16* __restrict__ vT,
                                              const float* __restrict__ mask,
                                              bf16* __restrict__ ctx) {
  __shared__ alignas(128) bf16 smem[20480];  // 40 KB
  bf16* Qs = smem;           // [64][64]   phase 1
  bf16* Ks = smem + 4096;    // [256][64]  phase 1
  bf16* Vs = smem;           // [64][256]  phase 2 (aliases Q/K region)
  bf16* Ps = smem + 16384;   // [4][16][32] phase 2
  const int tid = threadIdx.x, lane = tid & 63, wave = tid >> 6;
  int id = xcd_swz<768>(blockIdx.x + 8 * (blockIdx.y + 12 * blockIdx.z));
  const int q0 = (id & 7) * 64;
  const int h = (id >> 3) % 12, b = id / 96;
  const int bh = b * NHEADS + h;
  const bf16* qbase = qkv + (size_t)(b * SEQ) * H3 + h * DHEAD;
  const bf16* kbase = qbase + HDIM;
  const bf16* Vsrc = vT + (size_t)bh * DHEAD * SEQ;
  const int r15 = lane & 15, kg = lane >> 4;

  for (int s = tid; s < 512; s += 256) {
    int r = s >> 3, sl = s & 7;
    gld16(qbase + (size_t)(q0 + r) * H3 + ((sl ^ (r & 7)) << 3), &Qs[s * 8]);
  }
  f32x4 acc[32];
#pragma unroll
  for (int f = 0; f < 32; ++f) acc[f] = (f32x4){0.f, 0.f, 0.f, 0.f};

  for (int half = 0; half < 2; ++half) {
    for (int s = tid; s < 2048; s += 256) {
      int r = s >> 3, sl = s & 7;
      gld16(kbase + (size_t)(half * 256 + r) * H3 + ((sl ^ (r & 7)) << 3), &Ks[s * 8]);
    }
    __syncthreads();
#pragma unroll
    for (int ks = 0; ks < 2; ++ks) {
      int qrow = wave * 16 + r15;
      int sl = ks * 4 + kg;
      bf16x8 aq = *(const bf16x8*)(Qs + qrow * 64 + ((sl ^ (qrow & 7)) << 3));
#pragma unroll
      for (int nf = 0; nf < 16; ++nf) {
        int krow = nf * 16 + r15;
        bf16x8 bk = *(const bf16x8*)(Ks + krow * 64 + ((sl ^ (krow & 7)) << 3));
        acc[half * 16 + nf] =
            __builtin_amdgcn_mfma_f32_16x16x32_bf16(aq, bk, acc[half * 16 + nf], 0, 0, 0);
      }
    }
    __syncthreads();
  }

  // stage V half 0 into vacated LDS; loads fly during softmax
#pragma unroll
  for (int i = 0; i < 8; ++i) {
    int g16 = tid + i * 256;
    int d = g16 >> 5, c = g16 & 31;
    gld16(Vsrc + (size_t)d * SEQ + ((c ^ (d & 7)) << 3), &Vs[g16 * 8]);
  }

  const float* mrow = mask + b * SEQ;
#pragma unroll
  for (int f = 0; f < 32; ++f) {
    float mv = mrow[f * 16 + r15];
#pragma unroll
    for (int j = 0; j < 4; ++j) acc[f][j] = acc[f][j] * SCALE + mv;
  }
#pragma unroll
  for (int j = 0; j < 4; ++j) {
    float m = -1e30f;
#pragma unroll
    for (int f = 0; f < 32; ++f) m = fmaxf(m, acc[f][j]);
    m = fmaxf(m, __shfl_xor(m, 1));
    m = fmaxf(m, __shfl_xor(m, 2));
    m = fmaxf(m, __shfl_xor(m, 4));
    m = fmaxf(m, __shfl_xor(m, 8));
    float sum = 0.f;
#pragma unroll
    for (int f = 0; f < 32; ++f) { acc[f][j] = __expf(acc[f][j] - m); sum += acc[f][j]; }
    sum += __shfl_xor(sum, 1);
    sum += __shfl_xor(sum, 2);
    sum += __shfl_xor(sum, 4);
    sum += __shfl_xor(sum, 8);
    float inv = 1.0f / sum;
#pragma unroll
    for (int f = 0; f < 32; ++f) acc[f][j] *= inv;
  }
  __syncthreads();  // V half 0 staged

  f32x4 pvacc[4] = {};
  bf16* Pw = Ps + wave * (16 * 32);
#pragma unroll
  for (int half = 0; half < 2; ++half) {
    if (half == 1) {
      __syncthreads();
#pragma unroll
      for (int i = 0; i < 8; ++i) {
        int g16 = tid + i * 256;
        int d = g16 >> 5, c = g16 & 31;
        gld16(Vsrc + (size_t)d * SEQ + 256 + ((c ^ (d & 7)) << 3), &Vs[g16 * 8]);
      }
      __syncthreads();
    }
#pragma unroll
    for (int kc8 = 0; kc8 < 8; ++kc8) {
      int kc = half * 8 + kc8;
#pragma unroll
      for (int fb = 0; fb < 2; ++fb)
#pragma unroll
        for (int j = 0; j < 4; ++j) {
          int q = kg * 4 + j, k = fb * 16 + r15;
          Pw[q * 32 + ((((k >> 3) ^ ((q >> 1) & 3)) << 3) | (k & 7))] =
              (bf16)acc[kc * 2 + fb][j];
        }
      bf16x8 pa = *(const bf16x8*)(Pw + r15 * 32 + ((kg ^ ((r15 >> 1) & 3)) << 3));
#pragma unroll
      for (int n = 0; n < 4; ++n) {
        int d = n * 16 + r15;
        bf16x8 vb = *(const bf16x8*)(Vs + d * 256 + (((kc8 * 4 + kg) ^ (d & 7)) << 3));
        pvacc[n] = __builtin_amdgcn_mfma_f32_16x16x32_bf16(pa, vb, pvacc[n], 0, 0, 0);
      }
    }
  }

  bf16* crow = ctx + (size_t)(b * SEQ + q0 + wave * 16) * HDIM + h * DHEAD;
#pragma unroll
  for (int n = 0; n < 4; ++n)
#pragma unroll
    for (int j = 0; j < 4; ++j)
      crow[(size_t)(kg * 4 + j) * HDIM + n * 16 + r15] = (bf16)pvacc[n][j];
}

// ---------------- residual(bf16) + NP bf16 partials + bias + LayerNorm ----------------
// 192 threads/block (3 waves), 4 cols/thread, fully vectorized loads.
template <int NP>
__global__ __launch_bounds__(192) void k_ln4(const bf16* __restrict__ x,
                                             const bf16* __restrict__ d,   // [NP][MTOK*HDIM]
                                             const float* __restrict__ bias,
                                             const float* __restrict__ gamma,
                                             const float* __restrict__ beta,
                                             bf16* __restrict__ xo, float* __restrict__ fo) {
  const size_t MH = (size_t)MTOK * HDIM;
  int row = blockIdx.x;
  int t = threadIdx.x;
  int c = t * 4;
  const bf16* xr = x + (size_t)row * HDIM;
  const bf16* dr = d + (size_t)row * HDIM;
  union S4 { bf16 t[4]; short4 s; };
  S4 xv, dp[NP];
  xv.s = *(const short4*)(xr + c);
#pragma unroll
  for (int z = 0; z < NP; ++z) dp[z].s = *(const short4*)(dr + z * MH + c);
  float4 bv = *(const float4*)(bias + c);
  float a[4];
  float s1 = 0.f, s2 = 0.f;
#pragma unroll
  for (int j = 0; j < 4; ++j) {
    float b_ = (j == 0) ? bv.x : (j == 1) ? bv.y : (j == 2) ? bv.z : bv.w;
    a[j] = (float)xv.t[j] + b_;
#pragma unroll
    for (int z = 0; z < NP; ++z) a[j] += (float)dp[z].t[j];
    s1 += a[j]; s2 += a[j] * a[j];
  }
#pragma unroll
  for (int o = 32; o; o >>= 1) { s1 += __shfl_down(s1, o); s2 += __shfl_down(s2, o); }
  __shared__ float red[6];
  int wv = t >> 6, lane = t & 63;
  if (lane == 0) { red[wv] = s1; red[3 + wv] = s2; }
  __syncthreads();
  s1 = red[0] + red[1] + red[2];
  s2 = red[3] + red[4] + red[5];
  float mean = s1 * (1.0f / 768.0f);
  float var = s2 * (1.0f / 768.0f) - mean * mean;
  float rs = rsqrtf(var + 1e-12f);
  float4 gv = *(const float4*)(gamma + c);
  float4 btv = *(const float4*)(beta + c);
  float o0 = (a[0] - mean) * rs * gv.x + btv.x;
  float o1 = (a[1] - mean) * rs * gv.y + btv.y;
  float o2 = (a[2] - mean) * rs * gv.z + btv.z;
  float o3 = (a[3] - mean) * rs * gv.w + btv.w;
  S4 ov;
  ov.t[0] = (bf16)o0; ov.t[1] = (bf16)o1; ov.t[2] = (bf16)o2; ov.t[3] = (bf16)o3;
  *(short4*)(xo + (size_t)row * HDIM + c) = ov.s;
  if (fo) {
    float4 f4 = {o0, o1, o2, o3};
    *(float4*)(fo + (size_t)row * HDIM + c) = f4;
  }
}

// ---------------- host orchestration ----------------
extern "C" void kernel_launch(void* const* d_in, const int* in_sizes, int n_in,
                              void* d_out, int out_size, void* d_ws, size_t ws_size,
                              hipStream_t stream) {
  const float* hidden = (const float*)d_in[0];
  const float* mask   = (const float*)d_in[1];
  const float* nAg    = (const float*)d_in[2];
  const float* nAb    = (const float*)d_in[3];
  const float* nBg    = (const float*)d_in[4];
  const float* nBb    = (const float*)d_in[5];
  const float* wa     = (const float*)d_in[6];
  const float* ba     = (const float*)d_in[7];
  const float* wb     = (const float*)d_in[8];
  const float* bb     = (const float*)d_in[9];
  const float* wc     = (const float*)d_in[10];
  const float* bc     = (const float*)d_in[11];
  const float* wd     = (const float*)d_in[12];
  const float* bd     = (const float*)d_in[13];

  char* p = (char*)d_ws;
  auto alloc = [&](size_t bytes) {
    char* r = p;
    p += (bytes + 255) & ~(size_t)255;
    return (void*)r;
  };
  bf16* xb    = (bf16*)alloc((size_t)MTOK * HDIM * 2);   // bf16 residual stream
  bf16* qkv   = (bf16*)alloc((size_t)MTOK * H3 * 2);
  bf16* vT    = (bf16*)alloc((size_t)BATCH * NHEADS * DHEAD * SEQ * 2);
  bf16* ctx   = (bf16*)alloc((size_t)MTOK * HDIM * 2);
  bf16* hbuf  = (bf16*)alloc((size_t)MTOK * IDIM * 2);
  bf16* dres  = (bf16*)alloc((size_t)4 * MTOK * HDIM * 2);  // up to 4 bf16 split-K partials

  const size_t wa_n = (size_t)12 * H3 * HDIM;
  const size_t wb_n = (size_t)12 * HDIM * HDIM;
  const size_t wc_n = (size_t)12 * IDIM * HDIM;
  const size_t wd_n = (size_t)12 * HDIM * IDIM;
  size_t used = (size_t)(p - (char*)d_ws);
  const bool upfront = ws_size >= used + (wa_n + wb_n + wc_n + wd_n) * 2 + 8192;

  bf16* wab = (bf16*)alloc((upfront ? wa_n : (size_t)H3 * HDIM) * 2);
  bf16* wbb = (bf16*)alloc((upfront ? wb_n : (size_t)HDIM * HDIM) * 2);
  bf16* wcb = (bf16*)alloc((upfront ? wc_n : (size_t)IDIM * HDIM) * 2);
  bf16* wdb = (bf16*)alloc((upfront ? wd_n : (size_t)HDIM * IDIM) * 2);

  k_init_xb<<<1024, 256, 0, stream>>>(hidden, xb, (long)MTOK * HDIM / 8);
  if (upfront) {
    k_cvt<<<2048, 256, 0, stream>>>(wa, wab, (long)(wa_n / 8));
    k_cvt<<<2048, 256, 0, stream>>>(wb, wbb, (long)(wb_n / 8));
    k_cvt<<<2048, 256, 0, stream>>>(wc, wcb, (long)(wc_n / 8));
    k_cvt<<<2048, 256, 0, stream>>>(wd, wdb, (long)(wd_n / 8));
  }

  for (int l = 0; l < 12; ++l) {
    bf16* waL = upfront ? wab + (size_t)l * H3 * HDIM : wab;
    bf16* wbL = upfront ? wbb + (size_t)l * HDIM * HDIM : wbb;
    bf16* wcL = upfront ? wcb + (size_t)l * IDIM * HDIM : wcb;
    bf16* wdL = upfront ? wdb + (size_t)l * HDIM * IDIM : wdb;
    if (!upfront) {
      k_cvt<<<2048, 256, 0, stream>>>(wa + (size_t)l * H3 * HDIM, waL, (long)(H3 * HDIM / 8));
      k_cvt<<<2048, 256, 0, stream>>>(wb + (size_t)l * HDIM * HDIM, wbL, (long)(HDIM * HDIM / 8));
      k_cvt<<<2048, 256, 0, stream>>>(wc + (size_t)l * IDIM * HDIM, wcL, (long)(IDIM * HDIM / 8));
      k_cvt<<<2048, 256, 0, stream>>>(wd + (size_t)l * HDIM * IDIM, wdL, (long)(HDIM * IDIM / 8));
    }

    // QKV GEMM: Q,K rows -> qkv; V columns transposed straight to vT; bias fused
    k_gemm<3, 18, 32><<<dim3(18, 32), 256, 0, stream>>>(
        xb, waL, ba + (size_t)l * H3, qkv, vT, MTOK, H3, HDIM);
    k_attn<<<dim3(8, 12, 8), 256, 0, stream>>>(qkv, vT, mask, ctx);
    // attn proj: split-K2 (Kc=384), bf16 partials -> dres
    k_gemm_sk<6, 32, 2><<<dim3(6, 32, 2), 256, 0, stream>>>(
        ctx, wbL, dres, MTOK, HDIM, HDIM / 2, HDIM);
    k_ln4<2><<<MTOK, 192, 0, stream>>>(xb, dres, bb + (size_t)l * HDIM,
                                       nAg + (size_t)l * HDIM, nAb + (size_t)l * HDIM,
                                       xb, nullptr);
    // FFN1 + exact GELU -> hbuf (bf16), bias fused
    k_gemm<2, 24, 32><<<dim3(24, 32), 256, 0, stream>>>(
        xb, wcL, bc + (size_t)l * IDIM, hbuf, nullptr, MTOK, IDIM, HDIM);
    // FFN2: split-K4 (Kc=768), bf16 partials -> dres
    k_gemm_sk<6, 32, 4><<<dim3(6, 32, 4), 256, 0, stream>>>(
        hbuf, wdL, dres, MTOK, HDIM, IDIM / 4, IDIM);
    k_ln4<4><<<MTOK, 192, 0, stream>>>(xb, dres, bd + (size_t)l * HDIM,
                                       nBg + (size_t)l * HDIM, nBb + (size_t)l * HDIM,
                                       xb, (l == 11) ? (float*)d_out : nullptr);
  }
}

// Round 9
// 1886.503 us; speedup vs baseline: 1.2725x; 1.0072x over previous
//
#include <hip/hip_runtime.h>
#include <hip/hip_bf16.h>
#include <cmath>

typedef __bf16 bf16;
typedef __attribute__((ext_vector_type(8))) __bf16 bf16x8;
typedef __attribute__((ext_vector_type(4))) float f32x4;
typedef __attribute__((ext_vector_type(8))) short s16x8;

#define DEV __device__ __forceinline__

constexpr int HDIM = 768, NHEADS = 12, DHEAD = 64, IDIM = 3072, BATCH = 8, SEQ = 512;
constexpr int MTOK = BATCH * SEQ;   // 4096 tokens
constexpr int H3 = 3 * HDIM;        // 2304
constexpr float SCALE = 0.125f;     // 1/sqrt(64)

DEV void gld16(const bf16* g, bf16* l) {
  __builtin_amdgcn_global_load_lds((const __attribute__((address_space(1))) void*)g,
                                   (__attribute__((address_space(3))) void*)l, 16, 0, 0);
}

// tanh-form GELU via v_exp_f32: |err vs exact erf-GELU| < ~7e-4 abs, far below
// bf16 output rounding. ~8 VALU ops vs ~30 for __ocml_erf_f32.
DEV float gelu_f(float x) {
  float y = 1.5957691216f * (x + 0.044715f * x * x * x);  // 2*0.79788456*(x+c*x^3)
  float e = __expf(y);
  float t = 1.0f - 2.0f / (e + 1.0f);   // tanh(y/2)... y already doubled above
  return 0.5f * x * (1.0f + t);
}

// ---------------- weight conversion, one tensor: 8 f32 -> 8 bf16 per iter ----------------
__global__ void k_cvt(const float* __restrict__ s, bf16* __restrict__ o, long n8) {
  long i = (long)blockIdx.x * blockDim.x + threadIdx.x;
  long st = (long)gridDim.x * blockDim.x;
  for (; i < n8; i += st) {
    const float4* p = (const float4*)s + i * 2;
    float4 v0 = p[0], v1 = p[1];
    union { bf16 t[8]; s16x8 v; } u;
    u.t[0] = (bf16)v0.x; u.t[1] = (bf16)v0.y; u.t[2] = (bf16)v0.z; u.t[3] = (bf16)v0.w;
    u.t[4] = (bf16)v1.x; u.t[5] = (bf16)v1.y; u.t[6] = (bf16)v1.z; u.t[7] = (bf16)v1.w;
    *(s16x8*)(o + i * 8) = u.v;
  }
}

// ---------------- init: hidden f32 -> xb bf16 ----------------
__global__ void k_init_xb(const float* __restrict__ s, bf16* __restrict__ xb, long n8) {
  long i = (long)blockIdx.x * blockDim.x + threadIdx.x;
  long st = (long)gridDim.x * blockDim.x;
  for (; i < n8; i += st) {
    const float4* p = (const float4*)s + i * 2;
    float4 v0 = p[0], v1 = p[1];
    union { bf16 t[8]; s16x8 v; } u;
    u.t[0] = (bf16)v0.x; u.t[1] = (bf16)v0.y; u.t[2] = (bf16)v0.z; u.t[3] = (bf16)v0.w;
    u.t[4] = (bf16)v1.x; u.t[5] = (bf16)v1.y; u.t[6] = (bf16)v1.z; u.t[7] = (bf16)v1.w;
    *(s16x8*)(xb + i * 8) = u.v;
  }
}

// XCD-aware bijective remap: orig%8 = XCD (round-robin) -> contiguous tile chunk per XCD.
template <int NWG>
DEV int xcd_swz(int id) {
  static_assert(NWG % 8 == 0, "bijective swizzle needs nwg %% 8 == 0");
  return (id & 7) * (NWG / 8) + (id >> 3);
}

// ---------------- B^T GEMM (full K): C[M,N] = A[M,K] * W[N,K]^T + bias ----------------
// 128x128 tile, BK=32, 4 waves (2x2), both operands bf16 via global_load_lds
// (linear dest, pre-swizzled source, key (row>>1)&3 -> ~2-way LDS conflicts).
template <int OUT, int GX, int GY>  // OUT 1: bf16, 2: +GELU, 3: bf16 + V-transpose side-write
__global__ __launch_bounds__(256) void k_gemm(const bf16* __restrict__ A,
                                              const bf16* __restrict__ W,
                                              const float* __restrict__ bias,
                                              void* __restrict__ C,
                                              bf16* __restrict__ vt,
                                              int M, int N, int K) {
  __shared__ alignas(128) bf16 As[2][128 * 32];
  __shared__ alignas(128) bf16 Bs[2][128 * 32];
  const int tid = threadIdx.x;
  const int lane = tid & 63, wave = tid >> 6;
  const int wr = wave >> 1, wc = wave & 1;
  int id = xcd_swz<GX * GY>(blockIdx.x + GX * blockIdx.y);
  const int bx = id % GX, by = id / GX;
  const bf16* Ab = A + (size_t)by * 128 * K;
  const bf16* Bb = W + (size_t)bx * 128 * K;
  const int s0 = tid, s1 = tid + 256;
  const int r0 = s0 >> 2, c0 = ((s0 & 3) ^ ((r0 >> 1) & 3)) << 3;
  const int r1 = s1 >> 2, c1 = ((s1 & 3) ^ ((r1 >> 1) & 3)) << 3;

  f32x4 acc[4][4] = {};
  const int KT = K >> 5;
  int cur = 0;
  gld16(Ab + (size_t)r0 * K + c0, &As[0][s0 * 8]);
  gld16(Ab + (size_t)r1 * K + c1, &As[0][s1 * 8]);
  gld16(Bb + (size_t)r0 * K + c0, &Bs[0][s0 * 8]);
  gld16(Bb + (size_t)r1 * K + c1, &Bs[0][s1 * 8]);

  const int r = lane & 15, kg = lane >> 4;
  for (int kt = 0; kt < KT; ++kt) {
    __syncthreads();
    if (kt + 1 < KT) {
      int k0 = (kt + 1) << 5;
      gld16(Ab + (size_t)r0 * K + k0 + c0, &As[cur ^ 1][s0 * 8]);
      gld16(Ab + (size_t)r1 * K + k0 + c1, &As[cur ^ 1][s1 * 8]);
      gld16(Bb + (size_t)r0 * K + k0 + c0, &Bs[cur ^ 1][s0 * 8]);
      gld16(Bb + (size_t)r1 * K + k0 + c1, &Bs[cur ^ 1][s1 * 8]);
    }
    const bf16* Ac = As[cur];
    const bf16* Bc = Bs[cur];
    bf16x8 af[4], bfr[4];
#pragma unroll
    for (int m = 0; m < 4; ++m) {
      int row = wr * 64 + m * 16 + r;
      af[m] = *(const bf16x8*)(Ac + row * 32 + ((kg ^ ((row >> 1) & 3)) << 3));
    }
#pragma unroll
    for (int n = 0; n < 4; ++n) {
      int row = wc * 64 + n * 16 + r;
      bfr[n] = *(const bf16x8*)(Bc + row * 32 + ((kg ^ ((row >> 1) & 3)) << 3));
    }
#pragma unroll
    for (int m = 0; m < 4; ++m)
#pragma unroll
      for (int n = 0; n < 4; ++n)
        acc[m][n] = __builtin_amdgcn_mfma_f32_16x16x32_bf16(af[m], bfr[n], acc[m][n], 0, 0, 0);
    cur ^= 1;
  }
  const int g = lane >> 4, c16 = lane & 15;
#pragma unroll
  for (int m = 0; m < 4; ++m) {
#pragma unroll
    for (int n = 0; n < 4; ++n) {
      int col = bx * 128 + wc * 64 + n * 16 + c16;
      float bv = bias[col];
      if (OUT == 3 && col >= 2 * HDIM) {
        // V columns -> write transposed vT[(b,h),d,s], 4 consecutive s packed
        int hh = (col - 2 * HDIM) >> 6, dd = (col - 2 * HDIM) & 63;
        int row0 = by * 128 + wr * 64 + m * 16 + g * 4;
        int bb_ = row0 >> 9, ss = row0 & 511;
        union { bf16 t[4]; short4 q; } u;
#pragma unroll
        for (int j = 0; j < 4; ++j) u.t[j] = (bf16)(acc[m][n][j] + bv);
        *(short4*)(vt + (((size_t)(bb_ * NHEADS + hh) * DHEAD + dd) * SEQ + ss)) = u.q;
      } else {
#pragma unroll
        for (int j = 0; j < 4; ++j) {
          int row = by * 128 + wr * 64 + m * 16 + g * 4 + j;
          float v = acc[m][n][j] + bv;
          if (OUT == 2) v = gelu_f(v);
          ((bf16*)C)[(size_t)row * N + col] = (bf16)v;
        }
      }
    }
  }
}

// ---------------- split-K B^T GEMM: bf16 partials C_z[M,N] (summed in k_ln4) ----------
template <int GX, int GY, int GZ>
__global__ __launch_bounds__(256) void k_gemm_sk(const bf16* __restrict__ A,
                                                 const bf16* __restrict__ W,
                                                 bf16* __restrict__ C,
                                                 int M, int N, int Kc, int ld) {
  __shared__ alignas(128) bf16 As[2][128 * 32];
  __shared__ alignas(128) bf16 Bs[2][128 * 32];
  const int tid = threadIdx.x;
  const int lane = tid & 63, wave = tid >> 6;
  const int wr = wave >> 1, wc = wave & 1;
  int id = xcd_swz<GX * GY * GZ>(blockIdx.x + GX * (blockIdx.y + GY * blockIdx.z));
  const int bx = id % GX;
  const int t2 = id / GX;
  const int by = t2 % GY, kz = t2 / GY;
  const bf16* Ab = A + (size_t)by * 128 * ld + (size_t)kz * Kc;
  const bf16* Bb = W + (size_t)bx * 128 * ld + (size_t)kz * Kc;
  bf16* Cz = C + (size_t)kz * M * N;
  const int s0 = tid, s1 = tid + 256;
  const int r0 = s0 >> 2, c0 = ((s0 & 3) ^ ((r0 >> 1) & 3)) << 3;
  const int r1 = s1 >> 2, c1 = ((s1 & 3) ^ ((r1 >> 1) & 3)) << 3;

  f32x4 acc[4][4] = {};
  const int KT = Kc >> 5;
  int cur = 0;
  gld16(Ab + (size_t)r0 * ld + c0, &As[0][s0 * 8]);
  gld16(Ab + (size_t)r1 * ld + c1, &As[0][s1 * 8]);
  gld16(Bb + (size_t)r0 * ld + c0, &Bs[0][s0 * 8]);
  gld16(Bb + (size_t)r1 * ld + c1, &Bs[0][s1 * 8]);

  const int r = lane & 15, kg = lane >> 4;
  for (int kt = 0; kt < KT; ++kt) {
    __syncthreads();
    if (kt + 1 < KT) {
      int k0 = (kt + 1) << 5;
      gld16(Ab + (size_t)r0 * ld + k0 + c0, &As[cur ^ 1][s0 * 8]);
      gld16(Ab + (size_t)r1 * ld + k0 + c1, &As[cur ^ 1][s1 * 8]);
      gld16(Bb + (size_t)r0 * ld + k0 + c0, &Bs[cur ^ 1][s0 * 8]);
      gld16(Bb + (size_t)r1 * ld + k0 + c1, &Bs[cur ^ 1][s1 * 8]);
    }
    const bf16* Ac = As[cur];
    const bf16* Bc = Bs[cur];
    bf16x8 af[4], bfr[4];
#pragma unroll
    for (int m = 0; m < 4; ++m) {
      int row = wr * 64 + m * 16 + r;
      af[m] = *(const bf16x8*)(Ac + row * 32 + ((kg ^ ((row >> 1) & 3)) << 3));
    }
#pragma unroll
    for (int n = 0; n < 4; ++n) {
      int row = wc * 64 + n * 16 + r;
      bfr[n] = *(const bf16x8*)(Bc + row * 32 + ((kg ^ ((row >> 1) & 3)) << 3));
    }
#pragma unroll
    for (int m = 0; m < 4; ++m)
#pragma unroll
      for (int n = 0; n < 4; ++n)
        acc[m][n] = __builtin_amdgcn_mfma_f32_16x16x32_bf16(af[m], bfr[n], acc[m][n], 0, 0, 0);
    cur ^= 1;
  }
  const int g = lane >> 4, c16 = lane & 15;
#pragma unroll
  for (int m = 0; m < 4; ++m)
#pragma unroll
    for (int n = 0; n < 4; ++n) {
      int col = bx * 128 + wc * 64 + n * 16 + c16;
#pragma unroll
      for (int j = 0; j < 4; ++j) {
        int row = by * 128 + wr * 64 + m * 16 + g * 4 + j;
        Cz[(size_t)row * N + col] = (bf16)acc[m][n][j];
      }
    }
}

// ---------------- fused attention: scores + softmax + PV -> ctx ----------------
// grid linear 768 = 8 q-tiles x 12 heads x 8 batches; swizzled so the 8 q-tiles of one
// (b,h) (which share 128KB of K/V) land on one XCD's L2.
__global__ __launch_bounds__(256) void k_attn(const bf16* __restrict__ qkv,
                                              const bf16* __restrict__ vT,
                                              const float* __restrict__ mask,
                                              bf16* __restrict__ ctx) {
  __shared__ alignas(128) bf16 smem[20480];  // 40 KB
  bf16* Qs = smem;           // [64][64]   phase 1
  bf16* Ks = smem + 4096;    // [256][64]  phase 1
  bf16* Vs = smem;           // [64][256]  phase 2 (aliases Q/K region)
  bf16* Ps = smem + 16384;   // [4][16][32] phase 2
  const int tid = threadIdx.x, lane = tid & 63, wave = tid >> 6;
  int id = xcd_swz<768>(blockIdx.x + 8 * (blockIdx.y + 12 * blockIdx.z));
  const int q0 = (id & 7) * 64;
  const int h = (id >> 3) % 12, b = id / 96;
  const int bh = b * NHEADS + h;
  const bf16* qbase = qkv + (size_t)(b * SEQ) * H3 + h * DHEAD;
  const bf16* kbase = qbase + HDIM;
  const bf16* Vsrc = vT + (size_t)bh * DHEAD * SEQ;
  const int r15 = lane & 15, kg = lane >> 4;

  for (int s = tid; s < 512; s += 256) {
    int r = s >> 3, sl = s & 7;
    gld16(qbase + (size_t)(q0 + r) * H3 + ((sl ^ (r & 7)) << 3), &Qs[s * 8]);
  }
  f32x4 acc[32];
#pragma unroll
  for (int f = 0; f < 32; ++f) acc[f] = (f32x4){0.f, 0.f, 0.f, 0.f};

  for (int half = 0; half < 2; ++half) {
    for (int s = tid; s < 2048; s += 256) {
      int r = s >> 3, sl = s & 7;
      gld16(kbase + (size_t)(half * 256 + r) * H3 + ((sl ^ (r & 7)) << 3), &Ks[s * 8]);
    }
    __syncthreads();
#pragma unroll
    for (int ks = 0; ks < 2; ++ks) {
      int qrow = wave * 16 + r15;
      int sl = ks * 4 + kg;
      bf16x8 aq = *(const bf16x8*)(Qs + qrow * 64 + ((sl ^ (qrow & 7)) << 3));
#pragma unroll
      for (int nf = 0; nf < 16; ++nf) {
        int krow = nf * 16 + r15;
        bf16x8 bk = *(const bf16x8*)(Ks + krow * 64 + ((sl ^ (krow & 7)) << 3));
        acc[half * 16 + nf] =
            __builtin_amdgcn_mfma_f32_16x16x32_bf16(aq, bk, acc[half * 16 + nf], 0, 0, 0);
      }
    }
    __syncthreads();
  }

  // stage V half 0 into vacated LDS; loads fly during softmax
#pragma unroll
  for (int i = 0; i < 8; ++i) {
    int g16 = tid + i * 256;
    int d = g16 >> 5, c = g16 & 31;
    gld16(Vsrc + (size_t)d * SEQ + ((c ^ (d & 7)) << 3), &Vs[g16 * 8]);
  }

  const float* mrow = mask + b * SEQ;
#pragma unroll
  for (int f = 0; f < 32; ++f) {
    float mv = mrow[f * 16 + r15];
#pragma unroll
    for (int j = 0; j < 4; ++j) acc[f][j] = acc[f][j] * SCALE + mv;
  }
#pragma unroll
  for (int j = 0; j < 4; ++j) {
    float m = -1e30f;
#pragma unroll
    for (int f = 0; f < 32; ++f) m = fmaxf(m, acc[f][j]);
    m = fmaxf(m, __shfl_xor(m, 1));
    m = fmaxf(m, __shfl_xor(m, 2));
    m = fmaxf(m, __shfl_xor(m, 4));
    m = fmaxf(m, __shfl_xor(m, 8));
    float sum = 0.f;
#pragma unroll
    for (int f = 0; f < 32; ++f) { acc[f][j] = __expf(acc[f][j] - m); sum += acc[f][j]; }
    sum += __shfl_xor(sum, 1);
    sum += __shfl_xor(sum, 2);
    sum += __shfl_xor(sum, 4);
    sum += __shfl_xor(sum, 8);
    float inv = 1.0f / sum;
#pragma unroll
    for (int f = 0; f < 32; ++f) acc[f][j] *= inv;
  }
  __syncthreads();  // V half 0 staged

  f32x4 pvacc[4] = {};
  bf16* Pw = Ps + wave * (16 * 32);
#pragma unroll
  for (int half = 0; half < 2; ++half) {
    if (half == 1) {
      __syncthreads();
#pragma unroll
      for (int i = 0; i < 8; ++i) {
        int g16 = tid + i * 256;
        int d = g16 >> 5, c = g16 & 31;
        gld16(Vsrc + (size_t)d * SEQ + 256 + ((c ^ (d & 7)) << 3), &Vs[g16 * 8]);
      }
      __syncthreads();
    }
#pragma unroll
    for (int kc8 = 0; kc8 < 8; ++kc8) {
      int kc = half * 8 + kc8;
#pragma unroll
      for (int fb = 0; fb < 2; ++fb)
#pragma unroll
        for (int j = 0; j < 4; ++j) {
          int q = kg * 4 + j, k = fb * 16 + r15;
          Pw[q * 32 + ((((k >> 3) ^ ((q >> 1) & 3)) << 3) | (k & 7))] =
              (bf16)acc[kc * 2 + fb][j];
        }
      bf16x8 pa = *(const bf16x8*)(Pw + r15 * 32 + ((kg ^ ((r15 >> 1) & 3)) << 3));
#pragma unroll
      for (int n = 0; n < 4; ++n) {
        int d = n * 16 + r15;
        bf16x8 vb = *(const bf16x8*)(Vs + d * 256 + (((kc8 * 4 + kg) ^ (d & 7)) << 3));
        pvacc[n] = __builtin_amdgcn_mfma_f32_16x16x32_bf16(pa, vb, pvacc[n], 0, 0, 0);
      }
    }
  }

  bf16* crow = ctx + (size_t)(b * SEQ + q0 + wave * 16) * HDIM + h * DHEAD;
#pragma unroll
  for (int n = 0; n < 4; ++n)
#pragma unroll
    for (int j = 0; j < 4; ++j)
      crow[(size_t)(kg * 4 + j) * HDIM + n * 16 + r15] = (bf16)pvacc[n][j];
}

// ---------------- residual(bf16) + NP bf16 partials + bias + LayerNorm ----------------
// 192 threads/block (3 waves), 4 cols/thread, fully vectorized loads.
template <int NP>
__global__ __launch_bounds__(192) void k_ln4(const bf16* __restrict__ x,
                                             const bf16* __restrict__ d,   // [NP][MTOK*HDIM]
                                             const float* __restrict__ bias,
                                             const float* __restrict__ gamma,
                                             const float* __restrict__ beta,
                                             bf16* __restrict__ xo, float* __restrict__ fo) {
  const size_t MH = (size_t)MTOK * HDIM;
  int row = blockIdx.x;
  int t = threadIdx.x;
  int c = t * 4;
  const bf16* xr = x + (size_t)row * HDIM;
  const bf16* dr = d + (size_t)row * HDIM;
  union S4 { bf16 t[4]; short4 s; };
  S4 xv, dp[NP];
  xv.s = *(const short4*)(xr + c);
#pragma unroll
  for (int z = 0; z < NP; ++z) dp[z].s = *(const short4*)(dr + z * MH + c);
  float4 bv = *(const float4*)(bias + c);
  float a[4];
  float s1 = 0.f, s2 = 0.f;
#pragma unroll
  for (int j = 0; j < 4; ++j) {
    float b_ = (j == 0) ? bv.x : (j == 1) ? bv.y : (j == 2) ? bv.z : bv.w;
    a[j] = (float)xv.t[j] + b_;
#pragma unroll
    for (int z = 0; z < NP; ++z) a[j] += (float)dp[z].t[j];
    s1 += a[j]; s2 += a[j] * a[j];
  }
#pragma unroll
  for (int o = 32; o; o >>= 1) { s1 += __shfl_down(s1, o); s2 += __shfl_down(s2, o); }
  __shared__ float red[6];
  int wv = t >> 6, lane = t & 63;
  if (lane == 0) { red[wv] = s1; red[3 + wv] = s2; }
  __syncthreads();
  s1 = red[0] + red[1] + red[2];
  s2 = red[3] + red[4] + red[5];
  float mean = s1 * (1.0f / 768.0f);
  float var = s2 * (1.0f / 768.0f) - mean * mean;
  float rs = rsqrtf(var + 1e-12f);
  float4 gv = *(const float4*)(gamma + c);
  float4 btv = *(const float4*)(beta + c);
  float o0 = (a[0] - mean) * rs * gv.x + btv.x;
  float o1 = (a[1] - mean) * rs * gv.y + btv.y;
  float o2 = (a[2] - mean) * rs * gv.z + btv.z;
  float o3 = (a[3] - mean) * rs * gv.w + btv.w;
  S4 ov;
  ov.t[0] = (bf16)o0; ov.t[1] = (bf16)o1; ov.t[2] = (bf16)o2; ov.t[3] = (bf16)o3;
  *(short4*)(xo + (size_t)row * HDIM + c) = ov.s;
  if (fo) {
    float4 f4 = {o0, o1, o2, o3};
    *(float4*)(fo + (size_t)row * HDIM + c) = f4;
  }
}

// ---------------- host orchestration ----------------
extern "C" void kernel_launch(void* const* d_in, const int* in_sizes, int n_in,
                              void* d_out, int out_size, void* d_ws, size_t ws_size,
                              hipStream_t stream) {
  const float* hidden = (const float*)d_in[0];
  const float* mask   = (const float*)d_in[1];
  const float* nAg    = (const float*)d_in[2];
  const float* nAb    = (const float*)d_in[3];
  const float* nBg    = (const float*)d_in[4];
  const float* nBb    = (const float*)d_in[5];
  const float* wa     = (const float*)d_in[6];
  const float* ba     = (const float*)d_in[7];
  const float* wb     = (const float*)d_in[8];
  const float* bb     = (const float*)d_in[9];
  const float* wc     = (const float*)d_in[10];
  const float* bc     = (const float*)d_in[11];
  const float* wd     = (const float*)d_in[12];
  const float* bd     = (const float*)d_in[13];

  char* p = (char*)d_ws;
  auto alloc = [&](size_t bytes) {
    char* r = p;
    p += (bytes + 255) & ~(size_t)255;
    return (void*)r;
  };
  bf16* xb    = (bf16*)alloc((size_t)MTOK * HDIM * 2);   // bf16 residual stream
  bf16* qkv   = (bf16*)alloc((size_t)MTOK * H3 * 2);
  bf16* vT    = (bf16*)alloc((size_t)BATCH * NHEADS * DHEAD * SEQ * 2);
  bf16* ctx   = (bf16*)alloc((size_t)MTOK * HDIM * 2);
  bf16* hbuf  = (bf16*)alloc((size_t)MTOK * IDIM * 2);
  bf16* dres  = (bf16*)alloc((size_t)4 * MTOK * HDIM * 2);  // up to 4 bf16 split-K partials

  const size_t wa_n = (size_t)12 * H3 * HDIM;
  const size_t wb_n = (size_t)12 * HDIM * HDIM;
  const size_t wc_n = (size_t)12 * IDIM * HDIM;
  const size_t wd_n = (size_t)12 * HDIM * IDIM;
  size_t used = (size_t)(p - (char*)d_ws);
  const bool upfront = ws_size >= used + (wa_n + wb_n + wc_n + wd_n) * 2 + 8192;

  bf16* wab = (bf16*)alloc((upfront ? wa_n : (size_t)H3 * HDIM) * 2);
  bf16* wbb = (bf16*)alloc((upfront ? wb_n : (size_t)HDIM * HDIM) * 2);
  bf16* wcb = (bf16*)alloc((upfront ? wc_n : (size_t)IDIM * HDIM) * 2);
  bf16* wdb = (bf16*)alloc((upfront ? wd_n : (size_t)HDIM * IDIM) * 2);

  k_init_xb<<<1024, 256, 0, stream>>>(hidden, xb, (long)MTOK * HDIM / 8);
  if (upfront) {
    k_cvt<<<2048, 256, 0, stream>>>(wa, wab, (long)(wa_n / 8));
    k_cvt<<<2048, 256, 0, stream>>>(wb, wbb, (long)(wb_n / 8));
    k_cvt<<<2048, 256, 0, stream>>>(wc, wcb, (long)(wc_n / 8));
    k_cvt<<<2048, 256, 0, stream>>>(wd, wdb, (long)(wd_n / 8));
  }

  for (int l = 0; l < 12; ++l) {
    bf16* waL = upfront ? wab + (size_t)l * H3 * HDIM : wab;
    bf16* wbL = upfront ? wbb + (size_t)l * HDIM * HDIM : wbb;
    bf16* wcL = upfront ? wcb + (size_t)l * IDIM * HDIM : wcb;
    bf16* wdL = upfront ? wdb + (size_t)l * HDIM * IDIM : wdb;
    if (!upfront) {
      k_cvt<<<2048, 256, 0, stream>>>(wa + (size_t)l * H3 * HDIM, waL, (long)(H3 * HDIM / 8));
      k_cvt<<<2048, 256, 0, stream>>>(wb + (size_t)l * HDIM * HDIM, wbL, (long)(HDIM * HDIM / 8));
      k_cvt<<<2048, 256, 0, stream>>>(wc + (size_t)l * IDIM * HDIM, wcL, (long)(IDIM * HDIM / 8));
      k_cvt<<<2048, 256, 0, stream>>>(wd + (size_t)l * HDIM * IDIM, wdL, (long)(HDIM * IDIM / 8));
    }

    // QKV GEMM: Q,K rows -> qkv; V columns transposed straight to vT; bias fused
    k_gemm<3, 18, 32><<<dim3(18, 32), 256, 0, stream>>>(
        xb, waL, ba + (size_t)l * H3, qkv, vT, MTOK, H3, HDIM);
    k_attn<<<dim3(8, 12, 8), 256, 0, stream>>>(qkv, vT, mask, ctx);
    // attn proj: split-K2 (Kc=384), bf16 partials -> dres
    k_gemm_sk<6, 32, 2><<<dim3(6, 32, 2), 256, 0, stream>>>(
        ctx, wbL, dres, MTOK, HDIM, HDIM / 2, HDIM);
    k_ln4<2><<<MTOK, 192, 0, stream>>>(xb, dres, bb + (size_t)l * HDIM,
                                       nAg + (size_t)l * HDIM, nAb + (size_t)l * HDIM,
                                       xb, nullptr);
    // FFN1 + fast GELU -> hbuf (bf16), bias fused
    k_gemm<2, 24, 32><<<dim3(24, 32), 256, 0, stream>>>(
        xb, wcL, bc + (size_t)l * IDIM, hbuf, nullptr, MTOK, IDIM, HDIM);
    // FFN2: split-K4 (Kc=768), bf16 partials -> dres
    k_gemm_sk<6, 32, 4><<<dim3(6, 32, 4), 256, 0, stream>>>(
        hbuf, wdL, dres, MTOK, HDIM, IDIM / 4, IDIM);
    k_ln4<4><<<MTOK, 192, 0, stream>>>(xb, dres, bd + (size_t)l * HDIM,
                                       nBg + (size_t)l * HDIM, nBb + (size_t)l * HDIM,
                                       xb, (l == 11) ? (float*)d_out : nullptr);
  }
}